// Round 9
// baseline (672.417 us; speedup 1.0000x reference)
//
#include <hip/hip_runtime.h>
#include <hip/hip_bf16.h>
#include <hip/hip_fp16.h>

typedef _Float16 half_t;
typedef _Float16 h8 __attribute__((ext_vector_type(8)));
typedef _Float16 h4v __attribute__((ext_vector_type(4)));
typedef _Float16 h2v __attribute__((ext_vector_type(2)));
typedef float f4v __attribute__((ext_vector_type(4)));

union H8u { h8 v; h2v h2[4]; _Float16 e[8]; };
union H4u { h4v v; h2v h2[2]; _Float16 e[4]; };

static inline int cdiv(long a, long b) { return (int)((a + b - 1) / b); }

__device__ __forceinline__ void fma4(float4& a, float s, const float4& w) {
    a.x += s * w.x; a.y += s * w.y; a.z += s * w.z; a.w += s * w.w;
}

__device__ __forceinline__ h8 hmax8(h8 a, h8 b) {
#if __has_builtin(__builtin_elementwise_max)
    return __builtin_elementwise_max(a, b);
#else
    h8 r;
#pragma unroll
    for (int j = 0; j < 8; ++j) r[j] = (a[j] > b[j]) ? a[j] : b[j];
    return r;
#endif
}
__device__ __forceinline__ h4v hmax4(h4v a, h4v b) {
#if __has_builtin(__builtin_elementwise_max)
    return __builtin_elementwise_max(a, b);
#else
    h4v r;
#pragma unroll
    for (int j = 0; j < 4; ++j) r[j] = (a[j] > b[j]) ? a[j] : b[j];
    return r;
#endif
}

__device__ __forceinline__ float dot2acc(h2v a, h2v b, float c) {
#if __has_builtin(__builtin_amdgcn_fdot2)
    return __builtin_amdgcn_fdot2(a, b, c, false);
#else
    return c + (float)a.x * (float)b.x + (float)a.y * (float)b.y;
#endif
}

// ---------------- emb GEMM (fp32 compute, fp16 out) ----------------

template <int K4, int C4, int R>
__global__ __launch_bounds__(256) void gemm_t_h(
        const float* __restrict__ X, const float* __restrict__ W,
        const float* __restrict__ bias, half_t* __restrict__ Y,
        int Nr, int relu) {
    int idx = blockIdx.x * blockDim.x + threadIdx.x;
    int total = (Nr / R) * C4;
    if (idx >= total) return;
    int c4 = idx % C4;
    int n0 = (idx / C4) * R;
    const float4* __restrict__ Wv = (const float4*)W;
    const float4* __restrict__ Xv = (const float4*)X;
    float4 acc[R];
    float4 binit = bias ? ((const float4*)bias)[c4] : make_float4(0.f, 0.f, 0.f, 0.f);
#pragma unroll
    for (int r = 0; r < R; ++r) acc[r] = binit;
#pragma unroll 4
    for (int k4 = 0; k4 < K4; ++k4) {
        float4 w0 = Wv[(size_t)(4 * k4 + 0) * C4 + c4];
        float4 w1 = Wv[(size_t)(4 * k4 + 1) * C4 + c4];
        float4 w2 = Wv[(size_t)(4 * k4 + 2) * C4 + c4];
        float4 w3 = Wv[(size_t)(4 * k4 + 3) * C4 + c4];
#pragma unroll
        for (int r = 0; r < R; ++r) {
            float4 xv = Xv[(size_t)(n0 + r) * K4 + k4];
            fma4(acc[r], xv.x, w0); fma4(acc[r], xv.y, w1);
            fma4(acc[r], xv.z, w2); fma4(acc[r], xv.w, w3);
        }
    }
#pragma unroll
    for (int r = 0; r < R; ++r) {
        float4 o = acc[r];
        if (relu) {
            o.x = fmaxf(o.x, 0.f); o.y = fmaxf(o.y, 0.f);
            o.z = fmaxf(o.z, 0.f); o.w = fmaxf(o.w, 0.f);
        }
        h4v oh; oh.x = (half_t)o.x; oh.y = (half_t)o.y; oh.z = (half_t)o.z; oh.w = (half_t)o.w;
        ((h4v*)Y)[(size_t)(n0 + r) * C4 + c4] = oh;
    }
}

// ---------------- weight transpose+convert + att convert ----------------
// halfs: c1l[0,4096) c1r[4096,8192) c2l[8192,24576) c2r[24576,40960)
//        ggl[40960,45056) ggr[45056,49152)
//        att1[49152,49280) att2[49280,49408) attgg[49408,49440)

__global__ void wtrans(const float* __restrict__ c1l, const float* __restrict__ c1r,
                       const float* __restrict__ c2l, const float* __restrict__ c2r,
                       const float* __restrict__ ggl, const float* __restrict__ ggr,
                       const float* __restrict__ at1, const float* __restrict__ at2,
                       const float* __restrict__ atg, half_t* __restrict__ dst) {
    int idx = blockIdx.x * blockDim.x + threadIdx.x;
    if (idx >= 49440) return;
    if (idx >= 49152) {
        int j = idx - 49152;
        float v = (j < 128) ? at1[j] : (j < 256) ? at2[j - 128] : atg[j - 256];
        dst[idx] = (half_t)v;
        return;
    }
    const float* src; int K, loc;
    if (idx < 8192) {
        K = 32;
        if (idx < 4096) { src = c1l; loc = idx; } else { src = c1r; loc = idx - 4096; }
        int k = loc % K, c = loc / K;
        dst[idx] = (half_t)src[k * 128 + c];
    } else if (idx < 40960) {
        K = 128;
        if (idx < 24576) { src = c2l; loc = idx - 8192; } else { src = c2r; loc = idx - 24576; }
        int k = loc % K, c = loc / K;
        dst[idx] = (half_t)src[k * 128 + c];
    } else {
        K = 128;
        if (idx < 45056) { src = ggl; loc = idx - 40960; } else { src = ggr; loc = idx - 45056; }
        int k = loc % K, c = loc / K;
        dst[idx] = (half_t)src[k * 32 + c];
    }
}

// ---------------- MFMA dual GEMM ----------------

template <int K, int C1>
__global__ __launch_bounds__(256) void mfma_dual(
        const half_t* __restrict__ Xh,
        const half_t* __restrict__ W1t, const half_t* __restrict__ W2t,
        half_t* __restrict__ Y1, half_t* __restrict__ Y2, int Nr) {
    constexpr int KT = K / 32;
    constexpr int NBC = (2 * C1) / 64;
    int wave = threadIdx.x >> 6, lane = threadIdx.x & 63;
    int bCol = blockIdx.x % NBC;
    int bRow = blockIdx.x / NBC;
    int rowBase = bRow * 128 + wave * 32;
    int colBase = bCol * 64;
    int m = lane & 15, quad = lane >> 4;

    f4v acc[2][4] = {};

    const half_t* bptr[4];
#pragma unroll
    for (int nt = 0; nt < 4; ++nt) {
        int gc = colBase + nt * 16 + m;
        bptr[nt] = (gc < C1) ? (W1t + (size_t)gc * K) : (W2t + (size_t)(gc - C1) * K);
    }
    int r0 = rowBase + m, r1 = rowBase + 16 + m;
    int r0c = (r0 < Nr) ? r0 : (Nr - 1);
    int r1c = (r1 < Nr) ? r1 : (Nr - 1);
    const half_t* a0p = Xh + (size_t)r0c * K + quad * 8;
    const half_t* a1p = Xh + (size_t)r1c * K + quad * 8;

#pragma unroll
    for (int kk = 0; kk < KT; ++kk) {
        h8 a0 = *(const h8*)(a0p + kk * 32);
        h8 a1 = *(const h8*)(a1p + kk * 32);
#pragma unroll
        for (int nt = 0; nt < 4; ++nt) {
            h8 b = *(const h8*)(bptr[nt] + kk * 32 + quad * 8);
            acc[0][nt] = __builtin_amdgcn_mfma_f32_16x16x32_f16(a0, b, acc[0][nt], 0, 0, 0);
            acc[1][nt] = __builtin_amdgcn_mfma_f32_16x16x32_f16(a1, b, acc[1][nt], 0, 0, 0);
        }
    }

#pragma unroll
    for (int mt = 0; mt < 2; ++mt) {
#pragma unroll
        for (int nt = 0; nt < 4; ++nt) {
            int gc = colBase + nt * 16 + m;
            half_t* Y = (gc < C1) ? (Y1 + gc) : (Y2 + (gc - C1));
#pragma unroll
            for (int r = 0; r < 4; ++r) {
                int gr = rowBase + mt * 16 + quad * 4 + r;
                if (gr < Nr) Y[(size_t)gr * C1] = (half_t)acc[mt][nt][r];
            }
        }
    }
}

// ---------------- CSR construction ----------------

__global__ void count_dst(const int* __restrict__ ei, int* __restrict__ counts,
                          int E, int Etot) {
    int e = blockIdx.x * blockDim.x + threadIdx.x;
    if (e >= Etot) return;
    int d = (e < E) ? ei[E + e] : (e - E);
    atomicAdd(&counts[d], 1);
}

#define SCAN_CH 2048  // 256 threads x 8

__global__ void reduce_chunks(const int* __restrict__ counts, int* __restrict__ partial, int N) {
    __shared__ int sh[256];
    int t = threadIdx.x, base = blockIdx.x * SCAN_CH + t * 8;
    int s = 0;
    for (int j = 0; j < 8; ++j) if (base + j < N) s += counts[base + j];
    sh[t] = s; __syncthreads();
    for (int off = 128; off >= 1; off >>= 1) {
        if (t < off) sh[t] += sh[t + off];
        __syncthreads();
    }
    if (t == 0) partial[blockIdx.x] = sh[0];
}

// also zeroes the 64-bin degree histogram (runs before dhist_k)
__global__ void scan_partials(int* __restrict__ partial, int nch, int* __restrict__ dhist) {
    int t = threadIdx.x;
    if (t < 64) dhist[t] = 0;
    if (t == 0) {
        int run = 0;
        for (int i = 0; i < nch; ++i) { int v = partial[i]; partial[i] = run; run += v; }
    }
}

// writes running offsets into BOTH offsets and cursor (cursor is consumed by fill_adj)
__global__ void scan_chunks(const int* __restrict__ counts, const int* __restrict__ partial,
                            int* __restrict__ offsets, int* __restrict__ cursor, int N) {
    __shared__ int sh[256];
    int t = threadIdx.x, b = blockIdx.x, base = b * SCAN_CH + t * 8;
    int v[8], s = 0;
    for (int j = 0; j < 8; ++j) { v[j] = (base + j < N) ? counts[base + j] : 0; s += v[j]; }
    sh[t] = s; __syncthreads();
    for (int off = 1; off < 256; off <<= 1) {
        int x = (t >= off) ? sh[t - off] : 0;
        __syncthreads();
        sh[t] += x;
        __syncthreads();
    }
    int run = partial[b] + (t == 0 ? 0 : sh[t - 1]);
    for (int j = 0; j < 8; ++j) {
        if (base + j < N) { offsets[base + j] = run; cursor[base + j] = run; }
        run += v[j];
    }
}

// adj scatter: nontemporal store kills the cross-XCD partial-line write-back
// amplification (R8: 57.5 MB WRITE_SIZE for a 3.4 MB array).
__global__ void fill_adj(const int* __restrict__ ei, int* __restrict__ cursor,
                         int* __restrict__ adj, int E, int Etot) {
    int e = blockIdx.x * blockDim.x + threadIdx.x;
    if (e >= Etot) return;
    int s, d;
    if (e < E) { s = ei[e]; d = ei[E + e]; } else { s = e - E; d = s; }
    int pos = atomicAdd(&cursor[d], 1);
    __builtin_nontemporal_store(s, &adj[pos]);
}

// ---------------- degree-binned dst ordering (counting sort, 64 bins) ----------------

__global__ void dhist_k(const int* __restrict__ counts, int* __restrict__ dhist, int N) {
    int i = blockIdx.x * blockDim.x + threadIdx.x;
    if (i >= N) return;
    atomicAdd(&dhist[min(counts[i], 63)], 1);
}

__global__ void dscan(const int* __restrict__ dhist, int* __restrict__ dbase,
                      int* __restrict__ dstorder, int N, int Npad) {
    int t = threadIdx.x;
    if (t == 0) {
        int run = 0;
        for (int b = 0; b < 64; ++b) { dbase[b] = run; run += dhist[b]; }
    }
    if (N + t < Npad) dstorder[N + t] = -1;
}

__global__ void dscatter(const int* __restrict__ counts, int* __restrict__ dbase,
                         int* __restrict__ dstorder, int N) {
    int i = blockIdx.x * blockDim.x + threadIdx.x;
    if (i >= N) return;
    int p = atomicAdd(&dbase[min(counts[i], 63)], 1);
    dstorder[p] = i;
}

// ---------------- fused GATv2, 8 dsts/wave, 8 lanes/dst, degree-ordered ----------------

__global__ __launch_bounds__(256) void gat8_h4(
        const half_t* __restrict__ xl, const half_t* __restrict__ xr,
        const half_t* __restrict__ atth, const int* __restrict__ offsets,
        const int* __restrict__ counts, const int* __restrict__ adj,
        const int* __restrict__ dstorder,
        const float* __restrict__ bias, half_t* __restrict__ out, int N) {
    int wave = threadIdx.x >> 6, lane = threadIdx.x & 63;
    int g = lane >> 3, t = lane & 7;
    int idx = blockIdx.x * 32 + wave * 8 + g;
    int od = dstorder[idx];
    int dc = (od >= 0) ? od : 0;
    int off = offsets[dc];
    int deg = (od >= 0) ? counts[dc] : 0;
    int dmax = deg;
    dmax = max(dmax, __shfl_xor(dmax, 8));
    dmax = max(dmax, __shfl_xor(dmax, 16));
    dmax = max(dmax, __shfl_xor(dmax, 32));

    const half_t* xrp = xr + (size_t)dc * 128 + t * 16;
    h8 xr_lo = *(const h8*)(xrp);
    h8 xr_hi = *(const h8*)(xrp + 8);
    H8u at_lo, at_hi;
    at_lo.v = *(const h8*)(atth + t * 16);
    at_hi.v = *(const h8*)(atth + t * 16 + 8);

    float acc[16];
#pragma unroll
    for (int j = 0; j < 16; ++j) acc[j] = 0.f;
    float lsum = 0.f;
    h8 c02;
#pragma unroll
    for (int j = 0; j < 8; ++j) c02[j] = (half_t)0.2f;

    for (int i = 0; i < dmax; ++i) {
        bool valid = (i < deg);
        int s = adj[off + (valid ? i : 0)];
        const half_t* xp = xl + (size_t)s * 128 + t * 16;
        H8u a_lo, a_hi;
        a_lo.v = *(const h8*)(xp);
        a_hi.v = *(const h8*)(xp + 8);
        h8 v_lo = a_lo.v + xr_lo;
        h8 v_hi = a_hi.v + xr_hi;
        H8u lk_lo, lk_hi;
        lk_lo.v = hmax8(v_lo, v_lo * c02);
        lk_hi.v = hmax8(v_hi, v_hi * c02);
        float p = 0.f;
#pragma unroll
        for (int j = 0; j < 4; ++j) p = dot2acc(lk_lo.h2[j], at_lo.h2[j], p);
#pragma unroll
        for (int j = 0; j < 4; ++j) p = dot2acc(lk_hi.h2[j], at_hi.h2[j], p);
        p += __shfl_xor(p, 1);                 // head-pair sum -> head score
        float w = valid ? __expf(p) : 0.f;
        lsum += w;
#pragma unroll
        for (int j = 0; j < 8; ++j) acc[j] += w * (float)a_lo.e[j];
#pragma unroll
        for (int j = 0; j < 8; ++j) acc[8 + j] += w * (float)a_hi.e[j];
    }

    if (od >= 0) {
        float inv = 1.f / lsum;
        H8u o_lo, o_hi;
#pragma unroll
        for (int j = 0; j < 8; ++j)
            o_lo.e[j] = (half_t)fmaxf(acc[j] * inv + bias[t * 16 + j], 0.f);
#pragma unroll
        for (int j = 0; j < 8; ++j)
            o_hi.e[j] = (half_t)fmaxf(acc[8 + j] * inv + bias[t * 16 + 8 + j], 0.f);
        half_t* op = out + (size_t)od * 128 + t * 16;
        *(h8*)(op) = o_lo.v;
        *(h8*)(op + 8) = o_hi.v;
    }
}

__global__ __launch_bounds__(256) void gat8_h1(
        const half_t* __restrict__ xl, const half_t* __restrict__ xr,
        const half_t* __restrict__ atth, const int* __restrict__ offsets,
        const int* __restrict__ counts, const int* __restrict__ adj,
        const int* __restrict__ dstorder,
        const float* __restrict__ bias, float* __restrict__ out, int N) {
    int wave = threadIdx.x >> 6, lane = threadIdx.x & 63;
    int g = lane >> 3, t = lane & 7;
    int idx = blockIdx.x * 32 + wave * 8 + g;
    int od = dstorder[idx];
    int dc = (od >= 0) ? od : 0;
    int off = offsets[dc];
    int deg = (od >= 0) ? counts[dc] : 0;
    int dmax = deg;
    dmax = max(dmax, __shfl_xor(dmax, 8));
    dmax = max(dmax, __shfl_xor(dmax, 16));
    dmax = max(dmax, __shfl_xor(dmax, 32));

    h4v xr4 = *(const h4v*)(xr + (size_t)dc * 32 + t * 4);
    H4u at4; at4.v = *(const h4v*)(atth + t * 4);

    float acc[4] = {0.f, 0.f, 0.f, 0.f};
    float lsum = 0.f;
    h4v c02;
#pragma unroll
    for (int j = 0; j < 4; ++j) c02[j] = (half_t)0.2f;

    for (int i = 0; i < dmax; ++i) {
        bool valid = (i < deg);
        int s = adj[off + (valid ? i : 0)];
        H4u a; a.v = *(const h4v*)(xl + (size_t)s * 32 + t * 4);
        h4v v = a.v + xr4;
        H4u lk; lk.v = hmax4(v, v * c02);
        float p = dot2acc(lk.h2[0], at4.h2[0], 0.f);
        p = dot2acc(lk.h2[1], at4.h2[1], p);
        p += __shfl_xor(p, 1);
        p += __shfl_xor(p, 2);
        p += __shfl_xor(p, 4);
        float w = valid ? __expf(p) : 0.f;
        lsum += w;
#pragma unroll
        for (int j = 0; j < 4; ++j) acc[j] += w * (float)a.e[j];
    }

    if (od >= 0) {
        float inv = 1.f / lsum;
        float4 o;
        o.x = fmaxf(acc[0] * inv + bias[t * 4 + 0], 0.f);
        o.y = fmaxf(acc[1] * inv + bias[t * 4 + 1], 0.f);
        o.z = fmaxf(acc[2] * inv + bias[t * 4 + 2], 0.f);
        o.w = fmaxf(acc[3] * inv + bias[t * 4 + 3], 0.f);
        *(float4*)(out + (size_t)od * 32 + t * 4) = o;
    }
}

// ---------------- map branch ----------------

__global__ void map_sum_kernel(const float* __restrict__ lane_x, const float* __restrict__ map_W,
                               const float* __restrict__ map_b, float* __restrict__ sums, int M) {
    __shared__ float s[32];
    if (threadIdx.x < 32) s[threadIdx.x] = 0.f;
    __syncthreads();
    int t = blockIdx.x * blockDim.x + threadIdx.x;
    int nth = gridDim.x * blockDim.x;
    int c = t & 31;
    float w0 = map_W[c], w1 = map_W[32 + c], bb = map_b[c];
    float acc = 0.f;
    for (int m = t >> 5; m < M; m += nth >> 5) {
        float v = lane_x[(long)m * 2] * w0 + lane_x[(long)m * 2 + 1] * w1 + bb;
        acc += fmaxf(v, 0.f);
    }
    atomicAdd(&s[c], acc);
    __syncthreads();
    if (threadIdx.x < 32) atomicAdd(&sums[threadIdx.x], s[threadIdx.x]);
}

// ---------------- fused head ----------------

__global__ void head_kernel(const float* __restrict__ gf, const int* __restrict__ focal_idx,
                            const float* __restrict__ map_sums, int M,
                            const float* __restrict__ centerline, int L,
                            const float* __restrict__ cl_W, const float* __restrict__ cl_b,
                            const float* __restrict__ fc1_W, const float* __restrict__ fc1_b,
                            const float* __restrict__ fc2_W, const float* __restrict__ fc2_b,
                            const float* __restrict__ fco_W, const float* __restrict__ fco_b,
                            float* __restrict__ out) {
    int f = blockIdx.x;
    int lane = threadIdx.x;
    __shared__ float s_comb[96];
    __shared__ float s_h1[32];
    __shared__ float s_h2[16];
    __shared__ float s_cl[2];

    float c0 = 0.f, c1 = 0.f;
    if (lane < L) {
        c0 = centerline[((long)f * L + lane) * 2 + 0];
        c1 = centerline[((long)f * L + lane) * 2 + 1];
    }
    for (int off = 32; off >= 1; off >>= 1) {
        c0 += __shfl_down(c0, off);
        c1 += __shfl_down(c1, off);
    }
    if (lane == 0) { s_cl[0] = c0 / (float)L; s_cl[1] = c1 / (float)L; }
    __syncthreads();

    int fi = focal_idx[f];
    if (lane < 32) {
        s_comb[lane] = gf[(long)fi * 32 + lane];
        s_comb[32 + lane] = map_sums[lane] / (float)M;
        s_comb[64 + lane] = s_cl[0] * cl_W[lane] + s_cl[1] * cl_W[32 + lane] + cl_b[lane];
    }
    __syncthreads();

    if (lane < 32) {
        float acc = fc1_b[lane];
        for (int k = 0; k < 96; ++k) acc += s_comb[k] * fc1_W[k * 32 + lane];
        s_h1[lane] = fmaxf(acc, 0.f);
    }
    __syncthreads();

    if (lane < 16) {
        float acc = fc2_b[lane];
        for (int k = 0; k < 32; ++k) acc += s_h1[k] * fc2_W[k * 16 + lane];
        s_h2[lane] = fmaxf(acc, 0.f);
    }
    __syncthreads();

    if (lane < 60) {
        float acc = fco_b[lane];
        for (int k = 0; k < 16; ++k) acc += s_h2[k] * fco_W[k * 60 + lane];
        out[(long)f * 60 + lane] = acc;
    }
}

// ---------------- launch ----------------

extern "C" void kernel_launch(void* const* d_in, const int* in_sizes, int n_in,
                              void* d_out, int out_size, void* d_ws, size_t ws_size,
                              hipStream_t stream) {
    const float* x          = (const float*)d_in[0];
    const float* lane_x     = (const float*)d_in[1];
    const float* centerline = (const float*)d_in[2];
    const int*   ei         = (const int*)d_in[3];
    const int*   focal_idx  = (const int*)d_in[4];
    const float* emb_W = (const float*)d_in[5];
    const float* emb_b = (const float*)d_in[6];
    const float* c1_Wl = (const float*)d_in[7];
    const float* c1_Wr = (const float*)d_in[8];
    const float* c1_att = (const float*)d_in[9];
    const float* c1_b  = (const float*)d_in[10];
    const float* c2_Wl = (const float*)d_in[11];
    const float* c2_Wr = (const float*)d_in[12];
    const float* c2_att = (const float*)d_in[13];
    const float* c2_b  = (const float*)d_in[14];
    const float* map_W = (const float*)d_in[15];
    const float* map_b = (const float*)d_in[16];
    const float* gg_Wl = (const float*)d_in[17];
    const float* gg_Wr = (const float*)d_in[18];
    const float* gg_att = (const float*)d_in[19];
    const float* gg_b  = (const float*)d_in[20];
    const float* cl_W  = (const float*)d_in[21];
    const float* cl_b  = (const float*)d_in[22];
    const float* fc1_W = (const float*)d_in[23];
    const float* fc1_b = (const float*)d_in[24];
    const float* fc2_W = (const float*)d_in[25];
    const float* fc2_b = (const float*)d_in[26];
    const float* fco_W = (const float*)d_in[27];
    const float* fco_b = (const float*)d_in[28];

    const int N = in_sizes[0] / 60;
    const int M = in_sizes[1] / 2;
    const int F = in_sizes[4];
    const int L = in_sizes[2] / (F * 2);
    const int E = in_sizes[3] / 2;
    const int Etot = E + N;
    const int Npad = cdiv(N, 32) * 32;

    // Workspace layout:
    half_t* Xl_h = (half_t*)d_ws;                    // N*128
    half_t* Xr_h = Xl_h + (size_t)N * 128;           // N*128
    half_t* H0_h = Xr_h + (size_t)N * 128;           // N*32
    half_t* H1_h = H0_h + (size_t)N * 32;            // N*128
    half_t* AF_h = H1_h + (size_t)N * 128;           // N*128
    float*  GF_f = (float*)(AF_h + (size_t)N * 128); // N*32 f32
    half_t* Wt   = (half_t*)(GF_f + (size_t)N * 32); // 49440 halfs
    int* counts  = (int*)(Wt + 49440);               // N
    int* offsets = counts + N;                        // N
    int* cursor  = offsets + N;                       // N
    int* adj     = cursor + N;                        // Etot
    int* dstorder= adj + Etot;                        // Npad
    int* dhist   = dstorder + Npad;                   // 64
    int* dbase   = dhist + 64;                        // 64
    float* MAPS  = (float*)(dbase + 64);              // 32
    int* partial = (int*)(MAPS + 32);                 // nch

    half_t* c1Wlt = Wt + 0;
    half_t* c1Wrt = Wt + 4096;
    half_t* c2Wlt = Wt + 8192;
    half_t* c2Wrt = Wt + 24576;
    half_t* ggWlt = Wt + 40960;
    half_t* ggWrt = Wt + 45056;
    half_t* att1h = Wt + 49152;
    half_t* att2h = Wt + 49280;
    half_t* attgh = Wt + 49408;

    const int BS = 256;
    const int nch = cdiv(N, SCAN_CH);
    const int rowBlocks = cdiv(N, 128);

    // ---- CSR build + degree-bin ordering ----
    hipMemsetAsync(counts, 0, (size_t)N * sizeof(int), stream);
    count_dst<<<cdiv(Etot, BS), BS, 0, stream>>>(ei, counts, E, Etot);
    reduce_chunks<<<nch, 256, 0, stream>>>(counts, partial, N);
    scan_partials<<<1, 64, 0, stream>>>(partial, nch, dhist);
    scan_chunks<<<nch, 256, 0, stream>>>(counts, partial, offsets, cursor, N);
    fill_adj<<<cdiv(Etot, BS), BS, 0, stream>>>(ei, cursor, adj, E, Etot);
    dhist_k<<<cdiv(N, BS), BS, 0, stream>>>(counts, dhist, N);
    dscan<<<1, 64, 0, stream>>>(dhist, dbase, dstorder, N, Npad);
    dscatter<<<cdiv(N, BS), BS, 0, stream>>>(counts, dbase, dstorder, N);

    // ---- weights + att -> f16 ----
    wtrans<<<cdiv(49440, BS), BS, 0, stream>>>(c1_Wl, c1_Wr, c2_Wl, c2_Wr, gg_Wl, gg_Wr,
                                               c1_att, c2_att, gg_att, Wt);

    // ---- h0 = relu(x @ emb_W + emb_b) -> H0_h ----
    gemm_t_h<15, 8, 4><<<cdiv((long)(N / 4) * 8, BS), BS, 0, stream>>>(x, emb_W, emb_b, H0_h, N, 1);

    // ---- layer 1 (H=4) ----
    mfma_dual<32, 128><<<rowBlocks * 4, 256, 0, stream>>>(H0_h, c1Wlt, c1Wrt, Xl_h, Xr_h, N);
    gat8_h4<<<Npad / 32, 256, 0, stream>>>(Xl_h, Xr_h, att1h, offsets, counts, adj, dstorder, c1_b, H1_h, N);

    // ---- layer 2 (H=4) ----
    mfma_dual<128, 128><<<rowBlocks * 4, 256, 0, stream>>>(H1_h, c2Wlt, c2Wrt, Xl_h, Xr_h, N);
    gat8_h4<<<Npad / 32, 256, 0, stream>>>(Xl_h, Xr_h, att2h, offsets, counts, adj, dstorder, c2_b, AF_h, N);

    // ---- global graph (H=1) ----
    mfma_dual<128, 32><<<rowBlocks * 1, 256, 0, stream>>>(AF_h, ggWlt, ggWrt, Xl_h, Xr_h, N);
    gat8_h1<<<Npad / 32, 256, 0, stream>>>(Xl_h, Xr_h, attgh, offsets, counts, adj, dstorder, gg_b, GF_f, N);

    // ---- map branch ----
    hipMemsetAsync(MAPS, 0, 32 * sizeof(float), stream);
    map_sum_kernel<<<64, BS, 0, stream>>>(lane_x, map_W, map_b, MAPS, M);

    // ---- fused head ----
    head_kernel<<<F, 64, 0, stream>>>(GF_f, focal_idx, MAPS, M, centerline, L,
                                      cl_W, cl_b, fc1_W, fc1_b, fc2_W, fc2_b,
                                      fco_W, fco_b, (float*)d_out);
}

// Round 10
// 479.023 us; speedup vs baseline: 1.4037x; 1.4037x over previous
//
#include <hip/hip_runtime.h>
#include <hip/hip_bf16.h>
#include <hip/hip_fp16.h>

typedef _Float16 half_t;
typedef _Float16 h8 __attribute__((ext_vector_type(8)));
typedef _Float16 h4v __attribute__((ext_vector_type(4)));
typedef _Float16 h2v __attribute__((ext_vector_type(2)));
typedef float f4v __attribute__((ext_vector_type(4)));

union H8u { h8 v; h2v h2[4]; _Float16 e[8]; };
union H4u { h4v v; h2v h2[2]; _Float16 e[4]; };

static inline int cdiv(long a, long b) { return (int)((a + b - 1) / b); }

__device__ __forceinline__ void fma4(float4& a, float s, const float4& w) {
    a.x += s * w.x; a.y += s * w.y; a.z += s * w.z; a.w += s * w.w;
}

__device__ __forceinline__ h8 hmax8(h8 a, h8 b) {
#if __has_builtin(__builtin_elementwise_max)
    return __builtin_elementwise_max(a, b);
#else
    h8 r;
#pragma unroll
    for (int j = 0; j < 8; ++j) r[j] = (a[j] > b[j]) ? a[j] : b[j];
    return r;
#endif
}
__device__ __forceinline__ h4v hmax4(h4v a, h4v b) {
#if __has_builtin(__builtin_elementwise_max)
    return __builtin_elementwise_max(a, b);
#else
    h4v r;
#pragma unroll
    for (int j = 0; j < 4; ++j) r[j] = (a[j] > b[j]) ? a[j] : b[j];
    return r;
#endif
}

__device__ __forceinline__ float dot2acc(h2v a, h2v b, float c) {
#if __has_builtin(__builtin_amdgcn_fdot2)
    return __builtin_amdgcn_fdot2(a, b, c, false);
#else
    return c + (float)a.x * (float)b.x + (float)a.y * (float)b.y;
#endif
}

// ---------------- emb GEMM (fp32 compute, fp16 out) ----------------

template <int K4, int C4, int R>
__global__ __launch_bounds__(256) void gemm_t_h(
        const float* __restrict__ X, const float* __restrict__ W,
        const float* __restrict__ bias, half_t* __restrict__ Y,
        int Nr, int relu) {
    int idx = blockIdx.x * blockDim.x + threadIdx.x;
    int total = (Nr / R) * C4;
    if (idx >= total) return;
    int c4 = idx % C4;
    int n0 = (idx / C4) * R;
    const float4* __restrict__ Wv = (const float4*)W;
    const float4* __restrict__ Xv = (const float4*)X;
    float4 acc[R];
    float4 binit = bias ? ((const float4*)bias)[c4] : make_float4(0.f, 0.f, 0.f, 0.f);
#pragma unroll
    for (int r = 0; r < R; ++r) acc[r] = binit;
#pragma unroll 4
    for (int k4 = 0; k4 < K4; ++k4) {
        float4 w0 = Wv[(size_t)(4 * k4 + 0) * C4 + c4];
        float4 w1 = Wv[(size_t)(4 * k4 + 1) * C4 + c4];
        float4 w2 = Wv[(size_t)(4 * k4 + 2) * C4 + c4];
        float4 w3 = Wv[(size_t)(4 * k4 + 3) * C4 + c4];
#pragma unroll
        for (int r = 0; r < R; ++r) {
            float4 xv = Xv[(size_t)(n0 + r) * K4 + k4];
            fma4(acc[r], xv.x, w0); fma4(acc[r], xv.y, w1);
            fma4(acc[r], xv.z, w2); fma4(acc[r], xv.w, w3);
        }
    }
#pragma unroll
    for (int r = 0; r < R; ++r) {
        float4 o = acc[r];
        if (relu) {
            o.x = fmaxf(o.x, 0.f); o.y = fmaxf(o.y, 0.f);
            o.z = fmaxf(o.z, 0.f); o.w = fmaxf(o.w, 0.f);
        }
        h4v oh; oh.x = (half_t)o.x; oh.y = (half_t)o.y; oh.z = (half_t)o.z; oh.w = (half_t)o.w;
        ((h4v*)Y)[(size_t)(n0 + r) * C4 + c4] = oh;
    }
}

// ---------------- weight transpose+convert + att convert ----------------

__global__ void wtrans(const float* __restrict__ c1l, const float* __restrict__ c1r,
                       const float* __restrict__ c2l, const float* __restrict__ c2r,
                       const float* __restrict__ ggl, const float* __restrict__ ggr,
                       const float* __restrict__ at1, const float* __restrict__ at2,
                       const float* __restrict__ atg, half_t* __restrict__ dst) {
    int idx = blockIdx.x * blockDim.x + threadIdx.x;
    if (idx >= 49440) return;
    if (idx >= 49152) {
        int j = idx - 49152;
        float v = (j < 128) ? at1[j] : (j < 256) ? at2[j - 128] : atg[j - 256];
        dst[idx] = (half_t)v;
        return;
    }
    const float* src; int K, loc;
    if (idx < 8192) {
        K = 32;
        if (idx < 4096) { src = c1l; loc = idx; } else { src = c1r; loc = idx - 4096; }
        int k = loc % K, c = loc / K;
        dst[idx] = (half_t)src[k * 128 + c];
    } else if (idx < 40960) {
        K = 128;
        if (idx < 24576) { src = c2l; loc = idx - 8192; } else { src = c2r; loc = idx - 24576; }
        int k = loc % K, c = loc / K;
        dst[idx] = (half_t)src[k * 128 + c];
    } else {
        K = 128;
        if (idx < 45056) { src = ggl; loc = idx - 40960; } else { src = ggr; loc = idx - 45056; }
        int k = loc % K, c = loc / K;
        dst[idx] = (half_t)src[k * 32 + c];
    }
}

// ---------------- MFMA dual GEMM ----------------

template <int K, int C1>
__global__ __launch_bounds__(256) void mfma_dual(
        const half_t* __restrict__ Xh,
        const half_t* __restrict__ W1t, const half_t* __restrict__ W2t,
        half_t* __restrict__ Y1, half_t* __restrict__ Y2, int Nr) {
    constexpr int KT = K / 32;
    constexpr int NBC = (2 * C1) / 64;
    int wave = threadIdx.x >> 6, lane = threadIdx.x & 63;
    int bCol = blockIdx.x % NBC;
    int bRow = blockIdx.x / NBC;
    int rowBase = bRow * 128 + wave * 32;
    int colBase = bCol * 64;
    int m = lane & 15, quad = lane >> 4;

    f4v acc[2][4] = {};

    const half_t* bptr[4];
#pragma unroll
    for (int nt = 0; nt < 4; ++nt) {
        int gc = colBase + nt * 16 + m;
        bptr[nt] = (gc < C1) ? (W1t + (size_t)gc * K) : (W2t + (size_t)(gc - C1) * K);
    }
    int r0 = rowBase + m, r1 = rowBase + 16 + m;
    int r0c = (r0 < Nr) ? r0 : (Nr - 1);
    int r1c = (r1 < Nr) ? r1 : (Nr - 1);
    const half_t* a0p = Xh + (size_t)r0c * K + quad * 8;
    const half_t* a1p = Xh + (size_t)r1c * K + quad * 8;

#pragma unroll
    for (int kk = 0; kk < KT; ++kk) {
        h8 a0 = *(const h8*)(a0p + kk * 32);
        h8 a1 = *(const h8*)(a1p + kk * 32);
#pragma unroll
        for (int nt = 0; nt < 4; ++nt) {
            h8 b = *(const h8*)(bptr[nt] + kk * 32 + quad * 8);
            acc[0][nt] = __builtin_amdgcn_mfma_f32_16x16x32_f16(a0, b, acc[0][nt], 0, 0, 0);
            acc[1][nt] = __builtin_amdgcn_mfma_f32_16x16x32_f16(a1, b, acc[1][nt], 0, 0, 0);
        }
    }

#pragma unroll
    for (int mt = 0; mt < 2; ++mt) {
#pragma unroll
        for (int nt = 0; nt < 4; ++nt) {
            int gc = colBase + nt * 16 + m;
            half_t* Y = (gc < C1) ? (Y1 + gc) : (Y2 + (gc - C1));
#pragma unroll
            for (int r = 0; r < 4; ++r) {
                int gr = rowBase + mt * 16 + quad * 4 + r;
                if (gr < Nr) Y[(size_t)gr * C1] = (half_t)acc[mt][nt][r];
            }
        }
    }
}

// ---------------- CSR construction ----------------

__global__ void count_dst(const int* __restrict__ ei, int* __restrict__ counts,
                          int E, int Etot) {
    int e = blockIdx.x * blockDim.x + threadIdx.x;
    if (e >= Etot) return;
    int d = (e < E) ? ei[E + e] : (e - E);
    atomicAdd(&counts[d], 1);
}

#define SCAN_CH 2048  // 256 threads x 8

__global__ void reduce_chunks(const int* __restrict__ counts, int* __restrict__ partial, int N) {
    __shared__ int sh[256];
    int t = threadIdx.x, base = blockIdx.x * SCAN_CH + t * 8;
    int s = 0;
    for (int j = 0; j < 8; ++j) if (base + j < N) s += counts[base + j];
    sh[t] = s; __syncthreads();
    for (int off = 128; off >= 1; off >>= 1) {
        if (t < off) sh[t] += sh[t + off];
        __syncthreads();
    }
    if (t == 0) partial[blockIdx.x] = sh[0];
}

__global__ void scan_partials(int* __restrict__ partial, int nch) {
    if (threadIdx.x == 0 && blockIdx.x == 0) {
        int run = 0;
        for (int i = 0; i < nch; ++i) { int v = partial[i]; partial[i] = run; run += v; }
    }
}

// writes running offsets into BOTH offsets and cursor (cursor consumed by fill_adj)
__global__ void scan_chunks(const int* __restrict__ counts, const int* __restrict__ partial,
                            int* __restrict__ offsets, int* __restrict__ cursor, int N) {
    __shared__ int sh[256];
    int t = threadIdx.x, b = blockIdx.x, base = b * SCAN_CH + t * 8;
    int v[8], s = 0;
    for (int j = 0; j < 8; ++j) { v[j] = (base + j < N) ? counts[base + j] : 0; s += v[j]; }
    sh[t] = s; __syncthreads();
    for (int off = 1; off < 256; off <<= 1) {
        int x = (t >= off) ? sh[t - off] : 0;
        __syncthreads();
        sh[t] += x;
        __syncthreads();
    }
    int run = partial[b] + (t == 0 ? 0 : sh[t - 1]);
    for (int j = 0; j < 8; ++j) {
        if (base + j < N) { offsets[base + j] = run; cursor[base + j] = run; }
        run += v[j];
    }
}

// adj scatter: nontemporal store avoids cross-XCD partial-line write-back
// amplification (R8: 57.5 MB WRITE_SIZE for a 3.4 MB array).
__global__ void fill_adj(const int* __restrict__ ei, int* __restrict__ cursor,
                         int* __restrict__ adj, int E, int Etot) {
    int e = blockIdx.x * blockDim.x + threadIdx.x;
    if (e >= Etot) return;
    int s, d;
    if (e < E) { s = ei[e]; d = ei[E + e]; } else { s = e - E; d = s; }
    int pos = atomicAdd(&cursor[d], 1);
    __builtin_nontemporal_store(s, &adj[pos]);
}

// ---------------- degree-binned dst ordering, contention-free ----------------
// R9's global-atomic version serialized on 64 hot addresses (121 µs). This
// version: per-block LDS histograms -> per-(block,bin) bases -> LDS-cursor
// scatter. Zero global atomics.

__global__ __launch_bounds__(256) void hist_block(
        const int* __restrict__ counts, int* __restrict__ blockBins, int N) {
    __shared__ int sh[64];
    int t = threadIdx.x;
    if (t < 64) sh[t] = 0;
    __syncthreads();
    int i = blockIdx.x * 256 + t;
    if (i < N) atomicAdd(&sh[min(counts[i], 63)], 1);
    __syncthreads();
    if (t < 64) blockBins[blockIdx.x * 64 + t] = sh[t];
}

__global__ void bin_scan(const int* __restrict__ blockBins, int* __restrict__ blockBase,
                         int* __restrict__ dstorder, int nblk, int N, int Npad) {
    __shared__ int tot[64];
    __shared__ int dbase[64];
    int t = threadIdx.x;  // 64 threads
    int s = 0;
    for (int b = 0; b < nblk; ++b) s += blockBins[b * 64 + t];
    tot[t] = s;
    __syncthreads();
    if (t == 0) {
        int run = 0;
        for (int b = 0; b < 64; ++b) { dbase[b] = run; run += tot[b]; }
    }
    __syncthreads();
    int run = dbase[t];
    for (int b = 0; b < nblk; ++b) {
        blockBase[b * 64 + t] = run;
        run += blockBins[b * 64 + t];
    }
    if (N + t < Npad) dstorder[N + t] = -1;
}

__global__ __launch_bounds__(256) void scatter_block(
        const int* __restrict__ counts, const int* __restrict__ blockBase,
        int* __restrict__ dstorder, int N) {
    __shared__ int cur[64];
    int t = threadIdx.x;
    if (t < 64) cur[t] = blockBase[blockIdx.x * 64 + t];
    __syncthreads();
    int i = blockIdx.x * 256 + t;
    if (i < N) {
        int p = atomicAdd(&cur[min(counts[i], 63)], 1);
        __builtin_nontemporal_store(i, &dstorder[p]);
    }
}

// ---------------- fused GATv2, 8 dsts/wave, 8 lanes/dst, degree-ordered ----------------

__global__ __launch_bounds__(256) void gat8_h4(
        const half_t* __restrict__ xl, const half_t* __restrict__ xr,
        const half_t* __restrict__ atth, const int* __restrict__ offsets,
        const int* __restrict__ counts, const int* __restrict__ adj,
        const int* __restrict__ dstorder,
        const float* __restrict__ bias, half_t* __restrict__ out, int N) {
    int wave = threadIdx.x >> 6, lane = threadIdx.x & 63;
    int g = lane >> 3, t = lane & 7;
    int idx = blockIdx.x * 32 + wave * 8 + g;
    int od = dstorder[idx];
    int dc = (od >= 0) ? od : 0;
    int off = offsets[dc];
    int deg = (od >= 0) ? counts[dc] : 0;
    int dmax = deg;
    dmax = max(dmax, __shfl_xor(dmax, 8));
    dmax = max(dmax, __shfl_xor(dmax, 16));
    dmax = max(dmax, __shfl_xor(dmax, 32));

    const half_t* xrp = xr + (size_t)dc * 128 + t * 16;
    h8 xr_lo = *(const h8*)(xrp);
    h8 xr_hi = *(const h8*)(xrp + 8);
    H8u at_lo, at_hi;
    at_lo.v = *(const h8*)(atth + t * 16);
    at_hi.v = *(const h8*)(atth + t * 16 + 8);

    float acc[16];
#pragma unroll
    for (int j = 0; j < 16; ++j) acc[j] = 0.f;
    float lsum = 0.f;
    h8 c02;
#pragma unroll
    for (int j = 0; j < 8; ++j) c02[j] = (half_t)0.2f;

    for (int i = 0; i < dmax; ++i) {
        bool valid = (i < deg);
        int s = adj[off + (valid ? i : 0)];
        const half_t* xp = xl + (size_t)s * 128 + t * 16;
        H8u a_lo, a_hi;
        a_lo.v = *(const h8*)(xp);
        a_hi.v = *(const h8*)(xp + 8);
        h8 v_lo = a_lo.v + xr_lo;
        h8 v_hi = a_hi.v + xr_hi;
        H8u lk_lo, lk_hi;
        lk_lo.v = hmax8(v_lo, v_lo * c02);
        lk_hi.v = hmax8(v_hi, v_hi * c02);
        float p = 0.f;
#pragma unroll
        for (int j = 0; j < 4; ++j) p = dot2acc(lk_lo.h2[j], at_lo.h2[j], p);
#pragma unroll
        for (int j = 0; j < 4; ++j) p = dot2acc(lk_hi.h2[j], at_hi.h2[j], p);
        p += __shfl_xor(p, 1);                 // head-pair sum -> head score
        float w = valid ? __expf(p) : 0.f;
        lsum += w;
#pragma unroll
        for (int j = 0; j < 8; ++j) acc[j] += w * (float)a_lo.e[j];
#pragma unroll
        for (int j = 0; j < 8; ++j) acc[8 + j] += w * (float)a_hi.e[j];
    }

    if (od >= 0) {
        float inv = 1.f / lsum;
        H8u o_lo, o_hi;
#pragma unroll
        for (int j = 0; j < 8; ++j)
            o_lo.e[j] = (half_t)fmaxf(acc[j] * inv + bias[t * 16 + j], 0.f);
#pragma unroll
        for (int j = 0; j < 8; ++j)
            o_hi.e[j] = (half_t)fmaxf(acc[8 + j] * inv + bias[t * 16 + 8 + j], 0.f);
        half_t* op = out + (size_t)od * 128 + t * 16;
        *(h8*)(op) = o_lo.v;
        *(h8*)(op + 8) = o_hi.v;
    }
}

__global__ __launch_bounds__(256) void gat8_h1(
        const half_t* __restrict__ xl, const half_t* __restrict__ xr,
        const half_t* __restrict__ atth, const int* __restrict__ offsets,
        const int* __restrict__ counts, const int* __restrict__ adj,
        const int* __restrict__ dstorder,
        const float* __restrict__ bias, float* __restrict__ out, int N) {
    int wave = threadIdx.x >> 6, lane = threadIdx.x & 63;
    int g = lane >> 3, t = lane & 7;
    int idx = blockIdx.x * 32 + wave * 8 + g;
    int od = dstorder[idx];
    int dc = (od >= 0) ? od : 0;
    int off = offsets[dc];
    int deg = (od >= 0) ? counts[dc] : 0;
    int dmax = deg;
    dmax = max(dmax, __shfl_xor(dmax, 8));
    dmax = max(dmax, __shfl_xor(dmax, 16));
    dmax = max(dmax, __shfl_xor(dmax, 32));

    h4v xr4 = *(const h4v*)(xr + (size_t)dc * 32 + t * 4);
    H4u at4; at4.v = *(const h4v*)(atth + t * 4);

    float acc[4] = {0.f, 0.f, 0.f, 0.f};
    float lsum = 0.f;
    h4v c02;
#pragma unroll
    for (int j = 0; j < 4; ++j) c02[j] = (half_t)0.2f;

    for (int i = 0; i < dmax; ++i) {
        bool valid = (i < deg);
        int s = adj[off + (valid ? i : 0)];
        H4u a; a.v = *(const h4v*)(xl + (size_t)s * 32 + t * 4);
        h4v v = a.v + xr4;
        H4u lk; lk.v = hmax4(v, v * c02);
        float p = dot2acc(lk.h2[0], at4.h2[0], 0.f);
        p = dot2acc(lk.h2[1], at4.h2[1], p);
        p += __shfl_xor(p, 1);
        p += __shfl_xor(p, 2);
        p += __shfl_xor(p, 4);
        float w = valid ? __expf(p) : 0.f;
        lsum += w;
#pragma unroll
        for (int j = 0; j < 4; ++j) acc[j] += w * (float)a.e[j];
    }

    if (od >= 0) {
        float inv = 1.f / lsum;
        float4 o;
        o.x = fmaxf(acc[0] * inv + bias[t * 4 + 0], 0.f);
        o.y = fmaxf(acc[1] * inv + bias[t * 4 + 1], 0.f);
        o.z = fmaxf(acc[2] * inv + bias[t * 4 + 2], 0.f);
        o.w = fmaxf(acc[3] * inv + bias[t * 4 + 3], 0.f);
        *(float4*)(out + (size_t)od * 32 + t * 4) = o;
    }
}

// ---------------- map branch ----------------

__global__ void map_sum_kernel(const float* __restrict__ lane_x, const float* __restrict__ map_W,
                               const float* __restrict__ map_b, float* __restrict__ sums, int M) {
    __shared__ float s[32];
    if (threadIdx.x < 32) s[threadIdx.x] = 0.f;
    __syncthreads();
    int t = blockIdx.x * blockDim.x + threadIdx.x;
    int nth = gridDim.x * blockDim.x;
    int c = t & 31;
    float w0 = map_W[c], w1 = map_W[32 + c], bb = map_b[c];
    float acc = 0.f;
    for (int m = t >> 5; m < M; m += nth >> 5) {
        float v = lane_x[(long)m * 2] * w0 + lane_x[(long)m * 2 + 1] * w1 + bb;
        acc += fmaxf(v, 0.f);
    }
    atomicAdd(&s[c], acc);
    __syncthreads();
    if (threadIdx.x < 32) atomicAdd(&sums[threadIdx.x], s[threadIdx.x]);
}

// ---------------- fused head ----------------

__global__ void head_kernel(const float* __restrict__ gf, const int* __restrict__ focal_idx,
                            const float* __restrict__ map_sums, int M,
                            const float* __restrict__ centerline, int L,
                            const float* __restrict__ cl_W, const float* __restrict__ cl_b,
                            const float* __restrict__ fc1_W, const float* __restrict__ fc1_b,
                            const float* __restrict__ fc2_W, const float* __restrict__ fc2_b,
                            const float* __restrict__ fco_W, const float* __restrict__ fco_b,
                            float* __restrict__ out) {
    int f = blockIdx.x;
    int lane = threadIdx.x;
    __shared__ float s_comb[96];
    __shared__ float s_h1[32];
    __shared__ float s_h2[16];
    __shared__ float s_cl[2];

    float c0 = 0.f, c1 = 0.f;
    if (lane < L) {
        c0 = centerline[((long)f * L + lane) * 2 + 0];
        c1 = centerline[((long)f * L + lane) * 2 + 1];
    }
    for (int off = 32; off >= 1; off >>= 1) {
        c0 += __shfl_down(c0, off);
        c1 += __shfl_down(c1, off);
    }
    if (lane == 0) { s_cl[0] = c0 / (float)L; s_cl[1] = c1 / (float)L; }
    __syncthreads();

    int fi = focal_idx[f];
    if (lane < 32) {
        s_comb[lane] = gf[(long)fi * 32 + lane];
        s_comb[32 + lane] = map_sums[lane] / (float)M;
        s_comb[64 + lane] = s_cl[0] * cl_W[lane] + s_cl[1] * cl_W[32 + lane] + cl_b[lane];
    }
    __syncthreads();

    if (lane < 32) {
        float acc = fc1_b[lane];
        for (int k = 0; k < 96; ++k) acc += s_comb[k] * fc1_W[k * 32 + lane];
        s_h1[lane] = fmaxf(acc, 0.f);
    }
    __syncthreads();

    if (lane < 16) {
        float acc = fc2_b[lane];
        for (int k = 0; k < 32; ++k) acc += s_h1[k] * fc2_W[k * 16 + lane];
        s_h2[lane] = fmaxf(acc, 0.f);
    }
    __syncthreads();

    if (lane < 60) {
        float acc = fco_b[lane];
        for (int k = 0; k < 16; ++k) acc += s_h2[k] * fco_W[k * 60 + lane];
        out[(long)f * 60 + lane] = acc;
    }
}

// ---------------- launch ----------------

extern "C" void kernel_launch(void* const* d_in, const int* in_sizes, int n_in,
                              void* d_out, int out_size, void* d_ws, size_t ws_size,
                              hipStream_t stream) {
    const float* x          = (const float*)d_in[0];
    const float* lane_x     = (const float*)d_in[1];
    const float* centerline = (const float*)d_in[2];
    const int*   ei         = (const int*)d_in[3];
    const int*   focal_idx  = (const int*)d_in[4];
    const float* emb_W = (const float*)d_in[5];
    const float* emb_b = (const float*)d_in[6];
    const float* c1_Wl = (const float*)d_in[7];
    const float* c1_Wr = (const float*)d_in[8];
    const float* c1_att = (const float*)d_in[9];
    const float* c1_b  = (const float*)d_in[10];
    const float* c2_Wl = (const float*)d_in[11];
    const float* c2_Wr = (const float*)d_in[12];
    const float* c2_att = (const float*)d_in[13];
    const float* c2_b  = (const float*)d_in[14];
    const float* map_W = (const float*)d_in[15];
    const float* map_b = (const float*)d_in[16];
    const float* gg_Wl = (const float*)d_in[17];
    const float* gg_Wr = (const float*)d_in[18];
    const float* gg_att = (const float*)d_in[19];
    const float* gg_b  = (const float*)d_in[20];
    const float* cl_W  = (const float*)d_in[21];
    const float* cl_b  = (const float*)d_in[22];
    const float* fc1_W = (const float*)d_in[23];
    const float* fc1_b = (const float*)d_in[24];
    const float* fc2_W = (const float*)d_in[25];
    const float* fc2_b = (const float*)d_in[26];
    const float* fco_W = (const float*)d_in[27];
    const float* fco_b = (const float*)d_in[28];

    const int N = in_sizes[0] / 60;
    const int M = in_sizes[1] / 2;
    const int F = in_sizes[4];
    const int L = in_sizes[2] / (F * 2);
    const int E = in_sizes[3] / 2;
    const int Etot = E + N;
    const int Npad = cdiv(N, 32) * 32;
    const int nblk = cdiv(N, 256);

    // Workspace layout:
    half_t* Xl_h = (half_t*)d_ws;                    // N*128
    half_t* Xr_h = Xl_h + (size_t)N * 128;           // N*128
    half_t* H0_h = Xr_h + (size_t)N * 128;           // N*32
    half_t* H1_h = H0_h + (size_t)N * 32;            // N*128
    half_t* AF_h = H1_h + (size_t)N * 128;           // N*128
    float*  GF_f = (float*)(AF_h + (size_t)N * 128); // N*32 f32
    half_t* Wt   = (half_t*)(GF_f + (size_t)N * 32); // 49440 halfs
    int* counts  = (int*)(Wt + 49440);               // N
    int* offsets = counts + N;                        // N
    int* cursor  = offsets + N;                       // N
    int* adj     = cursor + N;                        // Etot
    int* dstorder= adj + Etot;                        // Npad
    int* blockBins = dstorder + Npad;                 // nblk*64
    int* blockBase = blockBins + nblk * 64;           // nblk*64
    float* MAPS  = (float*)(blockBase + nblk * 64);   // 32
    int* partial = (int*)(MAPS + 32);                 // nch

    half_t* c1Wlt = Wt + 0;
    half_t* c1Wrt = Wt + 4096;
    half_t* c2Wlt = Wt + 8192;
    half_t* c2Wrt = Wt + 24576;
    half_t* ggWlt = Wt + 40960;
    half_t* ggWrt = Wt + 45056;
    half_t* att1h = Wt + 49152;
    half_t* att2h = Wt + 49280;
    half_t* attgh = Wt + 49408;

    const int BS = 256;
    const int nch = cdiv(N, SCAN_CH);
    const int rowBlocks = cdiv(N, 128);

    // ---- CSR build + degree-bin ordering (contention-free) ----
    hipMemsetAsync(counts, 0, (size_t)N * sizeof(int), stream);
    count_dst<<<cdiv(Etot, BS), BS, 0, stream>>>(ei, counts, E, Etot);
    reduce_chunks<<<nch, 256, 0, stream>>>(counts, partial, N);
    scan_partials<<<1, 64, 0, stream>>>(partial, nch);
    scan_chunks<<<nch, 256, 0, stream>>>(counts, partial, offsets, cursor, N);
    fill_adj<<<cdiv(Etot, BS), BS, 0, stream>>>(ei, cursor, adj, E, Etot);
    hist_block<<<nblk, 256, 0, stream>>>(counts, blockBins, N);
    bin_scan<<<1, 64, 0, stream>>>(blockBins, blockBase, dstorder, nblk, N, Npad);
    scatter_block<<<nblk, 256, 0, stream>>>(counts, blockBase, dstorder, N);

    // ---- weights + att -> f16 ----
    wtrans<<<cdiv(49440, BS), BS, 0, stream>>>(c1_Wl, c1_Wr, c2_Wl, c2_Wr, gg_Wl, gg_Wr,
                                               c1_att, c2_att, gg_att, Wt);

    // ---- h0 = relu(x @ emb_W + emb_b) -> H0_h ----
    gemm_t_h<15, 8, 4><<<cdiv((long)(N / 4) * 8, BS), BS, 0, stream>>>(x, emb_W, emb_b, H0_h, N, 1);

    // ---- layer 1 (H=4) ----
    mfma_dual<32, 128><<<rowBlocks * 4, 256, 0, stream>>>(H0_h, c1Wlt, c1Wrt, Xl_h, Xr_h, N);
    gat8_h4<<<Npad / 32, 256, 0, stream>>>(Xl_h, Xr_h, att1h, offsets, counts, adj, dstorder, c1_b, H1_h, N);

    // ---- layer 2 (H=4) ----
    mfma_dual<128, 128><<<rowBlocks * 4, 256, 0, stream>>>(H1_h, c2Wlt, c2Wrt, Xl_h, Xr_h, N);
    gat8_h4<<<Npad / 32, 256, 0, stream>>>(Xl_h, Xr_h, att2h, offsets, counts, adj, dstorder, c2_b, AF_h, N);

    // ---- global graph (H=1) ----
    mfma_dual<128, 32><<<rowBlocks * 1, 256, 0, stream>>>(AF_h, ggWlt, ggWrt, Xl_h, Xr_h, N);
    gat8_h1<<<Npad / 32, 256, 0, stream>>>(Xl_h, Xr_h, attgh, offsets, counts, adj, dstorder, gg_b, GF_f, N);

    // ---- map branch ----
    hipMemsetAsync(MAPS, 0, 32 * sizeof(float), stream);
    map_sum_kernel<<<64, BS, 0, stream>>>(lane_x, map_W, map_b, MAPS, M);

    // ---- fused head ----
    head_kernel<<<F, 64, 0, stream>>>(GF_f, focal_idx, MAPS, M, centerline, L,
                                      cl_W, cl_b, fc1_W, fc1_b, fc2_W, fc2_b,
                                      fco_W, fco_b, (float*)d_out);
}

// Round 11
// 408.388 us; speedup vs baseline: 1.6465x; 1.1730x over previous
//
#include <hip/hip_runtime.h>
#include <hip/hip_bf16.h>
#include <hip/hip_fp16.h>

typedef _Float16 half_t;
typedef _Float16 h8 __attribute__((ext_vector_type(8)));
typedef _Float16 h4v __attribute__((ext_vector_type(4)));
typedef _Float16 h2v __attribute__((ext_vector_type(2)));
typedef float f4v __attribute__((ext_vector_type(4)));

union H8u { h8 v; h2v h2[4]; _Float16 e[8]; };
union H4u { h4v v; h2v h2[2]; _Float16 e[4]; };

static inline int cdiv(long a, long b) { return (int)((a + b - 1) / b); }

__device__ __forceinline__ void fma4(float4& a, float s, const float4& w) {
    a.x += s * w.x; a.y += s * w.y; a.z += s * w.z; a.w += s * w.w;
}

__device__ __forceinline__ h8 hmax8(h8 a, h8 b) {
#if __has_builtin(__builtin_elementwise_max)
    return __builtin_elementwise_max(a, b);
#else
    h8 r;
#pragma unroll
    for (int j = 0; j < 8; ++j) r[j] = (a[j] > b[j]) ? a[j] : b[j];
    return r;
#endif
}
__device__ __forceinline__ h4v hmax4(h4v a, h4v b) {
#if __has_builtin(__builtin_elementwise_max)
    return __builtin_elementwise_max(a, b);
#else
    h4v r;
#pragma unroll
    for (int j = 0; j < 4; ++j) r[j] = (a[j] > b[j]) ? a[j] : b[j];
    return r;
#endif
}

__device__ __forceinline__ float dot2acc(h2v a, h2v b, float c) {
#if __has_builtin(__builtin_amdgcn_fdot2)
    return __builtin_amdgcn_fdot2(a, b, c, false);
#else
    return c + (float)a.x * (float)b.x + (float)a.y * (float)b.y;
#endif
}

// ---------------- emb GEMM (fp32 compute, fp16 out) ----------------

template <int K4, int C4, int R>
__global__ __launch_bounds__(256) void gemm_t_h(
        const float* __restrict__ X, const float* __restrict__ W,
        const float* __restrict__ bias, half_t* __restrict__ Y,
        int Nr, int relu) {
    int idx = blockIdx.x * blockDim.x + threadIdx.x;
    int total = (Nr / R) * C4;
    if (idx >= total) return;
    int c4 = idx % C4;
    int n0 = (idx / C4) * R;
    const float4* __restrict__ Wv = (const float4*)W;
    const float4* __restrict__ Xv = (const float4*)X;
    float4 acc[R];
    float4 binit = bias ? ((const float4*)bias)[c4] : make_float4(0.f, 0.f, 0.f, 0.f);
#pragma unroll
    for (int r = 0; r < R; ++r) acc[r] = binit;
#pragma unroll 4
    for (int k4 = 0; k4 < K4; ++k4) {
        float4 w0 = Wv[(size_t)(4 * k4 + 0) * C4 + c4];
        float4 w1 = Wv[(size_t)(4 * k4 + 1) * C4 + c4];
        float4 w2 = Wv[(size_t)(4 * k4 + 2) * C4 + c4];
        float4 w3 = Wv[(size_t)(4 * k4 + 3) * C4 + c4];
#pragma unroll
        for (int r = 0; r < R; ++r) {
            float4 xv = Xv[(size_t)(n0 + r) * K4 + k4];
            fma4(acc[r], xv.x, w0); fma4(acc[r], xv.y, w1);
            fma4(acc[r], xv.z, w2); fma4(acc[r], xv.w, w3);
        }
    }
#pragma unroll
    for (int r = 0; r < R; ++r) {
        float4 o = acc[r];
        if (relu) {
            o.x = fmaxf(o.x, 0.f); o.y = fmaxf(o.y, 0.f);
            o.z = fmaxf(o.z, 0.f); o.w = fmaxf(o.w, 0.f);
        }
        h4v oh; oh.x = (half_t)o.x; oh.y = (half_t)o.y; oh.z = (half_t)o.z; oh.w = (half_t)o.w;
        ((h4v*)Y)[(size_t)(n0 + r) * C4 + c4] = oh;
    }
}

// ---------------- weight transpose+convert + att convert ----------------

__global__ void wtrans(const float* __restrict__ c1l, const float* __restrict__ c1r,
                       const float* __restrict__ c2l, const float* __restrict__ c2r,
                       const float* __restrict__ ggl, const float* __restrict__ ggr,
                       const float* __restrict__ at1, const float* __restrict__ at2,
                       const float* __restrict__ atg, half_t* __restrict__ dst) {
    int idx = blockIdx.x * blockDim.x + threadIdx.x;
    if (idx >= 49440) return;
    if (idx >= 49152) {
        int j = idx - 49152;
        float v = (j < 128) ? at1[j] : (j < 256) ? at2[j - 128] : atg[j - 256];
        dst[idx] = (half_t)v;
        return;
    }
    const float* src; int K, loc;
    if (idx < 8192) {
        K = 32;
        if (idx < 4096) { src = c1l; loc = idx; } else { src = c1r; loc = idx - 4096; }
        int k = loc % K, c = loc / K;
        dst[idx] = (half_t)src[k * 128 + c];
    } else if (idx < 40960) {
        K = 128;
        if (idx < 24576) { src = c2l; loc = idx - 8192; } else { src = c2r; loc = idx - 24576; }
        int k = loc % K, c = loc / K;
        dst[idx] = (half_t)src[k * 128 + c];
    } else {
        K = 128;
        if (idx < 45056) { src = ggl; loc = idx - 40960; } else { src = ggr; loc = idx - 45056; }
        int k = loc % K, c = loc / K;
        dst[idx] = (half_t)src[k * 32 + c];
    }
}

// ---------------- MFMA dual GEMM ----------------

template <int K, int C1>
__global__ __launch_bounds__(256) void mfma_dual(
        const half_t* __restrict__ Xh,
        const half_t* __restrict__ W1t, const half_t* __restrict__ W2t,
        half_t* __restrict__ Y1, half_t* __restrict__ Y2, int Nr) {
    constexpr int KT = K / 32;
    constexpr int NBC = (2 * C1) / 64;
    int wave = threadIdx.x >> 6, lane = threadIdx.x & 63;
    int bCol = blockIdx.x % NBC;
    int bRow = blockIdx.x / NBC;
    int rowBase = bRow * 128 + wave * 32;
    int colBase = bCol * 64;
    int m = lane & 15, quad = lane >> 4;

    f4v acc[2][4] = {};

    const half_t* bptr[4];
#pragma unroll
    for (int nt = 0; nt < 4; ++nt) {
        int gc = colBase + nt * 16 + m;
        bptr[nt] = (gc < C1) ? (W1t + (size_t)gc * K) : (W2t + (size_t)(gc - C1) * K);
    }
    int r0 = rowBase + m, r1 = rowBase + 16 + m;
    int r0c = (r0 < Nr) ? r0 : (Nr - 1);
    int r1c = (r1 < Nr) ? r1 : (Nr - 1);
    const half_t* a0p = Xh + (size_t)r0c * K + quad * 8;
    const half_t* a1p = Xh + (size_t)r1c * K + quad * 8;

#pragma unroll
    for (int kk = 0; kk < KT; ++kk) {
        h8 a0 = *(const h8*)(a0p + kk * 32);
        h8 a1 = *(const h8*)(a1p + kk * 32);
#pragma unroll
        for (int nt = 0; nt < 4; ++nt) {
            h8 b = *(const h8*)(bptr[nt] + kk * 32 + quad * 8);
            acc[0][nt] = __builtin_amdgcn_mfma_f32_16x16x32_f16(a0, b, acc[0][nt], 0, 0, 0);
            acc[1][nt] = __builtin_amdgcn_mfma_f32_16x16x32_f16(a1, b, acc[1][nt], 0, 0, 0);
        }
    }

#pragma unroll
    for (int mt = 0; mt < 2; ++mt) {
#pragma unroll
        for (int nt = 0; nt < 4; ++nt) {
            int gc = colBase + nt * 16 + m;
            half_t* Y = (gc < C1) ? (Y1 + gc) : (Y2 + (gc - C1));
#pragma unroll
            for (int r = 0; r < 4; ++r) {
                int gr = rowBase + mt * 16 + quad * 4 + r;
                if (gr < Nr) Y[(size_t)gr * C1] = (half_t)acc[mt][nt][r];
            }
        }
    }
}

// ---------------- CSR construction ----------------
// Self-loops are prefilled deterministically in scan_chunks (softmax is
// permutation-invariant, so in-segment order doesn't matter); count_dst and
// fill_adj only touch the E real edges.

__global__ void count_dst(const int* __restrict__ ei, int* __restrict__ counts, int E) {
    int e = blockIdx.x * blockDim.x + threadIdx.x;
    if (e >= E) return;
    atomicAdd(&counts[ei[E + e]], 1);
}

#define SCAN_CH 2048  // 256 threads x 8

__global__ void reduce_chunks(const int* __restrict__ counts, int* __restrict__ partial, int N) {
    __shared__ int sh[256];
    int t = threadIdx.x, base = blockIdx.x * SCAN_CH + t * 8;
    int s = 0;
    for (int j = 0; j < 8; ++j) if (base + j < N) s += counts[base + j] + 1;  // +1 self-loop
    sh[t] = s; __syncthreads();
    for (int off = 128; off >= 1; off >>= 1) {
        if (t < off) sh[t] += sh[t + off];
        __syncthreads();
    }
    if (t == 0) partial[blockIdx.x] = sh[0];
}

__global__ void scan_partials(int* __restrict__ partial, int nch) {
    if (threadIdx.x == 0 && blockIdx.x == 0) {
        int run = 0;
        for (int i = 0; i < nch; ++i) { int v = partial[i]; partial[i] = run; run += v; }
    }
}

// Writes offsets; seeds cursor past the self-loop; prefills the self-loop
// into adj (ordered, ~one touch per line); updates counts to true degree.
__global__ void scan_chunks(int* __restrict__ counts, const int* __restrict__ partial,
                            int* __restrict__ offsets, int* __restrict__ cursor,
                            int* __restrict__ adj, int N) {
    __shared__ int sh[256];
    int t = threadIdx.x, b = blockIdx.x, base = b * SCAN_CH + t * 8;
    int v[8], s = 0;
    for (int j = 0; j < 8; ++j) {
        v[j] = (base + j < N) ? (counts[base + j] + 1) : 0;
        s += v[j];
    }
    sh[t] = s; __syncthreads();
    for (int off = 1; off < 256; off <<= 1) {
        int x = (t >= off) ? sh[t - off] : 0;
        __syncthreads();
        sh[t] += x;
        __syncthreads();
    }
    int run = partial[b] + (t == 0 ? 0 : sh[t - 1]);
    for (int j = 0; j < 8; ++j) {
        if (base + j < N) {
            offsets[base + j] = run;
            adj[run] = base + j;       // self-loop first
            cursor[base + j] = run + 1;
            counts[base + j] = v[j];   // true degree (incl. self-loop)
        }
        run += v[j];
    }
}

__global__ void fill_adj(const int* __restrict__ ei, int* __restrict__ cursor,
                         int* __restrict__ adj, int E) {
    int e = blockIdx.x * blockDim.x + threadIdx.x;
    if (e >= E) return;
    int s = ei[e], d = ei[E + e];
    int pos = atomicAdd(&cursor[d], 1);
    adj[pos] = s;
}

// ---------------- fused GATv2, 8 dsts/wave, 8 lanes/dst ----------------
// H=4: lane t (0..7) owns channels [16t,16t+16); head = t>>1; head score =
// own dot + shfl_xor(1). leaky(v) = max(v, 0.2v) exactly. No online max
// (scores bounded, softmax shift-invariant). Packed fp16 channel math,
// f32 score/weight/accumulators.

__global__ __launch_bounds__(256) void gat8_h4(
        const half_t* __restrict__ xl, const half_t* __restrict__ xr,
        const half_t* __restrict__ atth, const int* __restrict__ offsets,
        const int* __restrict__ counts, const int* __restrict__ adj,
        const float* __restrict__ bias, half_t* __restrict__ out, int N) {
    int wave = threadIdx.x >> 6, lane = threadIdx.x & 63;
    int g = lane >> 3, t = lane & 7;
    int d = blockIdx.x * 32 + wave * 8 + g;
    int dc = (d < N) ? d : (N - 1);
    int off = offsets[dc];
    int deg = (d < N) ? counts[dc] : 0;
    int dmax = deg;
    dmax = max(dmax, __shfl_xor(dmax, 8));
    dmax = max(dmax, __shfl_xor(dmax, 16));
    dmax = max(dmax, __shfl_xor(dmax, 32));

    const half_t* xrp = xr + (size_t)dc * 128 + t * 16;
    h8 xr_lo = *(const h8*)(xrp);
    h8 xr_hi = *(const h8*)(xrp + 8);
    H8u at_lo, at_hi;
    at_lo.v = *(const h8*)(atth + t * 16);
    at_hi.v = *(const h8*)(atth + t * 16 + 8);

    float acc[16];
#pragma unroll
    for (int j = 0; j < 16; ++j) acc[j] = 0.f;
    float lsum = 0.f;
    h8 c02;
#pragma unroll
    for (int j = 0; j < 8; ++j) c02[j] = (half_t)0.2f;

    for (int i = 0; i < dmax; ++i) {
        bool valid = (i < deg);
        int s = adj[off + (valid ? i : 0)];
        const half_t* xp = xl + (size_t)s * 128 + t * 16;
        H8u a_lo, a_hi;
        a_lo.v = *(const h8*)(xp);
        a_hi.v = *(const h8*)(xp + 8);
        h8 v_lo = a_lo.v + xr_lo;
        h8 v_hi = a_hi.v + xr_hi;
        H8u lk_lo, lk_hi;
        lk_lo.v = hmax8(v_lo, v_lo * c02);
        lk_hi.v = hmax8(v_hi, v_hi * c02);
        float p = 0.f;
#pragma unroll
        for (int j = 0; j < 4; ++j) p = dot2acc(lk_lo.h2[j], at_lo.h2[j], p);
#pragma unroll
        for (int j = 0; j < 4; ++j) p = dot2acc(lk_hi.h2[j], at_hi.h2[j], p);
        p += __shfl_xor(p, 1);                 // head-pair sum -> head score
        float w = valid ? __expf(p) : 0.f;
        lsum += w;
#pragma unroll
        for (int j = 0; j < 8; ++j) acc[j] += w * (float)a_lo.e[j];
#pragma unroll
        for (int j = 0; j < 8; ++j) acc[8 + j] += w * (float)a_hi.e[j];
    }

    if (d < N) {
        float inv = 1.f / lsum;
        H8u o_lo, o_hi;
#pragma unroll
        for (int j = 0; j < 8; ++j)
            o_lo.e[j] = (half_t)fmaxf(acc[j] * inv + bias[t * 16 + j], 0.f);
#pragma unroll
        for (int j = 0; j < 8; ++j)
            o_hi.e[j] = (half_t)fmaxf(acc[8 + j] * inv + bias[t * 16 + 8 + j], 0.f);
        half_t* op = out + (size_t)d * 128 + t * 16;
        *(h8*)(op) = o_lo.v;
        *(h8*)(op + 8) = o_hi.v;
    }
}

__global__ __launch_bounds__(256) void gat8_h1(
        const half_t* __restrict__ xl, const half_t* __restrict__ xr,
        const half_t* __restrict__ atth, const int* __restrict__ offsets,
        const int* __restrict__ counts, const int* __restrict__ adj,
        const float* __restrict__ bias, float* __restrict__ out, int N) {
    int wave = threadIdx.x >> 6, lane = threadIdx.x & 63;
    int g = lane >> 3, t = lane & 7;
    int d = blockIdx.x * 32 + wave * 8 + g;
    int dc = (d < N) ? d : (N - 1);
    int off = offsets[dc];
    int deg = (d < N) ? counts[dc] : 0;
    int dmax = deg;
    dmax = max(dmax, __shfl_xor(dmax, 8));
    dmax = max(dmax, __shfl_xor(dmax, 16));
    dmax = max(dmax, __shfl_xor(dmax, 32));

    h4v xr4 = *(const h4v*)(xr + (size_t)dc * 32 + t * 4);
    H4u at4; at4.v = *(const h4v*)(atth + t * 4);

    float acc[4] = {0.f, 0.f, 0.f, 0.f};
    float lsum = 0.f;
    h4v c02;
#pragma unroll
    for (int j = 0; j < 4; ++j) c02[j] = (half_t)0.2f;

    for (int i = 0; i < dmax; ++i) {
        bool valid = (i < deg);
        int s = adj[off + (valid ? i : 0)];
        H4u a; a.v = *(const h4v*)(xl + (size_t)s * 32 + t * 4);
        h4v v = a.v + xr4;
        H4u lk; lk.v = hmax4(v, v * c02);
        float p = dot2acc(lk.h2[0], at4.h2[0], 0.f);
        p = dot2acc(lk.h2[1], at4.h2[1], p);
        p += __shfl_xor(p, 1);
        p += __shfl_xor(p, 2);
        p += __shfl_xor(p, 4);
        float w = valid ? __expf(p) : 0.f;
        lsum += w;
#pragma unroll
        for (int j = 0; j < 4; ++j) acc[j] += w * (float)a.e[j];
    }

    if (d < N) {
        float inv = 1.f / lsum;
        float4 o;
        o.x = fmaxf(acc[0] * inv + bias[t * 4 + 0], 0.f);
        o.y = fmaxf(acc[1] * inv + bias[t * 4 + 1], 0.f);
        o.z = fmaxf(acc[2] * inv + bias[t * 4 + 2], 0.f);
        o.w = fmaxf(acc[3] * inv + bias[t * 4 + 3], 0.f);
        *(float4*)(out + (size_t)d * 32 + t * 4) = o;
    }
}

// ---------------- map branch ----------------

__global__ void map_sum_kernel(const float* __restrict__ lane_x, const float* __restrict__ map_W,
                               const float* __restrict__ map_b, float* __restrict__ sums, int M) {
    __shared__ float s[32];
    if (threadIdx.x < 32) s[threadIdx.x] = 0.f;
    __syncthreads();
    int t = blockIdx.x * blockDim.x + threadIdx.x;
    int nth = gridDim.x * blockDim.x;
    int c = t & 31;
    float w0 = map_W[c], w1 = map_W[32 + c], bb = map_b[c];
    float acc = 0.f;
    for (int m = t >> 5; m < M; m += nth >> 5) {
        float v = lane_x[(long)m * 2] * w0 + lane_x[(long)m * 2 + 1] * w1 + bb;
        acc += fmaxf(v, 0.f);
    }
    atomicAdd(&s[c], acc);
    __syncthreads();
    if (threadIdx.x < 32) atomicAdd(&sums[threadIdx.x], s[threadIdx.x]);
}

// ---------------- fused head ----------------

__global__ void head_kernel(const float* __restrict__ gf, const int* __restrict__ focal_idx,
                            const float* __restrict__ map_sums, int M,
                            const float* __restrict__ centerline, int L,
                            const float* __restrict__ cl_W, const float* __restrict__ cl_b,
                            const float* __restrict__ fc1_W, const float* __restrict__ fc1_b,
                            const float* __restrict__ fc2_W, const float* __restrict__ fc2_b,
                            const float* __restrict__ fco_W, const float* __restrict__ fco_b,
                            float* __restrict__ out) {
    int f = blockIdx.x;
    int lane = threadIdx.x;
    __shared__ float s_comb[96];
    __shared__ float s_h1[32];
    __shared__ float s_h2[16];
    __shared__ float s_cl[2];

    float c0 = 0.f, c1 = 0.f;
    if (lane < L) {
        c0 = centerline[((long)f * L + lane) * 2 + 0];
        c1 = centerline[((long)f * L + lane) * 2 + 1];
    }
    for (int off = 32; off >= 1; off >>= 1) {
        c0 += __shfl_down(c0, off);
        c1 += __shfl_down(c1, off);
    }
    if (lane == 0) { s_cl[0] = c0 / (float)L; s_cl[1] = c1 / (float)L; }
    __syncthreads();

    int fi = focal_idx[f];
    if (lane < 32) {
        s_comb[lane] = gf[(long)fi * 32 + lane];
        s_comb[32 + lane] = map_sums[lane] / (float)M;
        s_comb[64 + lane] = s_cl[0] * cl_W[lane] + s_cl[1] * cl_W[32 + lane] + cl_b[lane];
    }
    __syncthreads();

    if (lane < 32) {
        float acc = fc1_b[lane];
        for (int k = 0; k < 96; ++k) acc += s_comb[k] * fc1_W[k * 32 + lane];
        s_h1[lane] = fmaxf(acc, 0.f);
    }
    __syncthreads();

    if (lane < 16) {
        float acc = fc2_b[lane];
        for (int k = 0; k < 32; ++k) acc += s_h1[k] * fc2_W[k * 16 + lane];
        s_h2[lane] = fmaxf(acc, 0.f);
    }
    __syncthreads();

    if (lane < 60) {
        float acc = fco_b[lane];
        for (int k = 0; k < 16; ++k) acc += s_h2[k] * fco_W[k * 60 + lane];
        out[(long)f * 60 + lane] = acc;
    }
}

// ---------------- launch ----------------

extern "C" void kernel_launch(void* const* d_in, const int* in_sizes, int n_in,
                              void* d_out, int out_size, void* d_ws, size_t ws_size,
                              hipStream_t stream) {
    const float* x          = (const float*)d_in[0];
    const float* lane_x     = (const float*)d_in[1];
    const float* centerline = (const float*)d_in[2];
    const int*   ei         = (const int*)d_in[3];
    const int*   focal_idx  = (const int*)d_in[4];
    const float* emb_W = (const float*)d_in[5];
    const float* emb_b = (const float*)d_in[6];
    const float* c1_Wl = (const float*)d_in[7];
    const float* c1_Wr = (const float*)d_in[8];
    const float* c1_att = (const float*)d_in[9];
    const float* c1_b  = (const float*)d_in[10];
    const float* c2_Wl = (const float*)d_in[11];
    const float* c2_Wr = (const float*)d_in[12];
    const float* c2_att = (const float*)d_in[13];
    const float* c2_b  = (const float*)d_in[14];
    const float* map_W = (const float*)d_in[15];
    const float* map_b = (const float*)d_in[16];
    const float* gg_Wl = (const float*)d_in[17];
    const float* gg_Wr = (const float*)d_in[18];
    const float* gg_att = (const float*)d_in[19];
    const float* gg_b  = (const float*)d_in[20];
    const float* cl_W  = (const float*)d_in[21];
    const float* cl_b  = (const float*)d_in[22];
    const float* fc1_W = (const float*)d_in[23];
    const float* fc1_b = (const float*)d_in[24];
    const float* fc2_W = (const float*)d_in[25];
    const float* fc2_b = (const float*)d_in[26];
    const float* fco_W = (const float*)d_in[27];
    const float* fco_b = (const float*)d_in[28];

    const int N = in_sizes[0] / 60;
    const int M = in_sizes[1] / 2;
    const int F = in_sizes[4];
    const int L = in_sizes[2] / (F * 2);
    const int E = in_sizes[3] / 2;
    const int Etot = E + N;

    // Workspace layout:
    half_t* Xl_h = (half_t*)d_ws;                    // N*128
    half_t* Xr_h = Xl_h + (size_t)N * 128;           // N*128
    half_t* H0_h = Xr_h + (size_t)N * 128;           // N*32
    half_t* H1_h = H0_h + (size_t)N * 32;            // N*128
    half_t* AF_h = H1_h + (size_t)N * 128;           // N*128
    float*  GF_f = (float*)(AF_h + (size_t)N * 128); // N*32 f32
    half_t* Wt   = (half_t*)(GF_f + (size_t)N * 32); // 49440 halfs
    int* counts  = (int*)(Wt + 49440);               // N
    int* offsets = counts + N;                        // N
    int* cursor  = offsets + N;                       // N
    int* adj     = cursor + N;                        // Etot
    float* MAPS  = (float*)(adj + Etot);              // 32
    int* partial = (int*)(MAPS + 32);                 // nch

    half_t* c1Wlt = Wt + 0;
    half_t* c1Wrt = Wt + 4096;
    half_t* c2Wlt = Wt + 8192;
    half_t* c2Wrt = Wt + 24576;
    half_t* ggWlt = Wt + 40960;
    half_t* ggWrt = Wt + 45056;
    half_t* att1h = Wt + 49152;
    half_t* att2h = Wt + 49280;
    half_t* attgh = Wt + 49408;

    const int BS = 256;
    const int nch = cdiv(N, SCAN_CH);
    const int rowBlocks = cdiv(N, 128);

    // ---- CSR build (self-loops prefilled in scan_chunks) ----
    hipMemsetAsync(counts, 0, (size_t)N * sizeof(int), stream);
    count_dst<<<cdiv(E, BS), BS, 0, stream>>>(ei, counts, E);
    reduce_chunks<<<nch, 256, 0, stream>>>(counts, partial, N);
    scan_partials<<<1, 64, 0, stream>>>(partial, nch);
    scan_chunks<<<nch, 256, 0, stream>>>(counts, partial, offsets, cursor, adj, N);
    fill_adj<<<cdiv(E, BS), BS, 0, stream>>>(ei, cursor, adj, E);

    // ---- weights + att -> f16 ----
    wtrans<<<cdiv(49440, BS), BS, 0, stream>>>(c1_Wl, c1_Wr, c2_Wl, c2_Wr, gg_Wl, gg_Wr,
                                               c1_att, c2_att, gg_att, Wt);

    // ---- h0 = relu(x @ emb_W + emb_b) -> H0_h ----
    gemm_t_h<15, 8, 4><<<cdiv((long)(N / 4) * 8, BS), BS, 0, stream>>>(x, emb_W, emb_b, H0_h, N, 1);

    // ---- layer 1 (H=4) ----
    mfma_dual<32, 128><<<rowBlocks * 4, 256, 0, stream>>>(H0_h, c1Wlt, c1Wrt, Xl_h, Xr_h, N);
    gat8_h4<<<cdiv(N, 32), 256, 0, stream>>>(Xl_h, Xr_h, att1h, offsets, counts, adj, c1_b, H1_h, N);

    // ---- layer 2 (H=4) ----
    mfma_dual<128, 128><<<rowBlocks * 4, 256, 0, stream>>>(H1_h, c2Wlt, c2Wrt, Xl_h, Xr_h, N);
    gat8_h4<<<cdiv(N, 32), 256, 0, stream>>>(Xl_h, Xr_h, att2h, offsets, counts, adj, c2_b, AF_h, N);

    // ---- global graph (H=1) ----
    mfma_dual<128, 32><<<rowBlocks * 1, 256, 0, stream>>>(AF_h, ggWlt, ggWrt, Xl_h, Xr_h, N);
    gat8_h1<<<cdiv(N, 32), 256, 0, stream>>>(Xl_h, Xr_h, attgh, offsets, counts, adj, gg_b, GF_f, N);

    // ---- map branch ----
    hipMemsetAsync(MAPS, 0, 32 * sizeof(float), stream);
    map_sum_kernel<<<64, BS, 0, stream>>>(lane_x, map_W, map_b, MAPS, M);

    // ---- fused head ----
    head_kernel<<<F, 64, 0, stream>>>(GF_f, focal_idx, MAPS, M, centerline, L,
                                      cl_W, cl_b, fc1_W, fc1_b, fc2_W, fc2_b,
                                      fco_W, fco_b, (float*)d_out);
}

// Round 12
// 399.605 us; speedup vs baseline: 1.6827x; 1.0220x over previous
//
#include <hip/hip_runtime.h>
#include <hip/hip_bf16.h>
#include <hip/hip_fp16.h>

typedef _Float16 half_t;
typedef _Float16 h8 __attribute__((ext_vector_type(8)));
typedef _Float16 h4v __attribute__((ext_vector_type(4)));
typedef _Float16 h2v __attribute__((ext_vector_type(2)));
typedef float f4v __attribute__((ext_vector_type(4)));

union H8u { h8 v; h2v h2[4]; _Float16 e[8]; };
union H4u { h4v v; h2v h2[2]; _Float16 e[4]; };

static inline int cdiv(long a, long b) { return (int)((a + b - 1) / b); }

__device__ __forceinline__ void fma4(float4& a, float s, const float4& w) {
    a.x += s * w.x; a.y += s * w.y; a.z += s * w.z; a.w += s * w.w;
}

__device__ __forceinline__ h8 hmax8(h8 a, h8 b) {
#if __has_builtin(__builtin_elementwise_max)
    return __builtin_elementwise_max(a, b);
#else
    h8 r;
#pragma unroll
    for (int j = 0; j < 8; ++j) r[j] = (a[j] > b[j]) ? a[j] : b[j];
    return r;
#endif
}
__device__ __forceinline__ h4v hmax4(h4v a, h4v b) {
#if __has_builtin(__builtin_elementwise_max)
    return __builtin_elementwise_max(a, b);
#else
    h4v r;
#pragma unroll
    for (int j = 0; j < 4; ++j) r[j] = (a[j] > b[j]) ? a[j] : b[j];
    return r;
#endif
}

__device__ __forceinline__ float dot2acc(h2v a, h2v b, float c) {
#if __has_builtin(__builtin_amdgcn_fdot2)
    return __builtin_amdgcn_fdot2(a, b, c, false);
#else
    return c + (float)a.x * (float)b.x + (float)a.y * (float)b.y;
#endif
}

// ---------------- emb GEMM (fp32 compute, fp16 out) ----------------

template <int K4, int C4, int R>
__global__ __launch_bounds__(256) void gemm_t_h(
        const float* __restrict__ X, const float* __restrict__ W,
        const float* __restrict__ bias, half_t* __restrict__ Y,
        int Nr, int relu) {
    int idx = blockIdx.x * blockDim.x + threadIdx.x;
    int total = (Nr / R) * C4;
    if (idx >= total) return;
    int c4 = idx % C4;
    int n0 = (idx / C4) * R;
    const float4* __restrict__ Wv = (const float4*)W;
    const float4* __restrict__ Xv = (const float4*)X;
    float4 acc[R];
    float4 binit = bias ? ((const float4*)bias)[c4] : make_float4(0.f, 0.f, 0.f, 0.f);
#pragma unroll
    for (int r = 0; r < R; ++r) acc[r] = binit;
#pragma unroll 4
    for (int k4 = 0; k4 < K4; ++k4) {
        float4 w0 = Wv[(size_t)(4 * k4 + 0) * C4 + c4];
        float4 w1 = Wv[(size_t)(4 * k4 + 1) * C4 + c4];
        float4 w2 = Wv[(size_t)(4 * k4 + 2) * C4 + c4];
        float4 w3 = Wv[(size_t)(4 * k4 + 3) * C4 + c4];
#pragma unroll
        for (int r = 0; r < R; ++r) {
            float4 xv = Xv[(size_t)(n0 + r) * K4 + k4];
            fma4(acc[r], xv.x, w0); fma4(acc[r], xv.y, w1);
            fma4(acc[r], xv.z, w2); fma4(acc[r], xv.w, w3);
        }
    }
#pragma unroll
    for (int r = 0; r < R; ++r) {
        float4 o = acc[r];
        if (relu) {
            o.x = fmaxf(o.x, 0.f); o.y = fmaxf(o.y, 0.f);
            o.z = fmaxf(o.z, 0.f); o.w = fmaxf(o.w, 0.f);
        }
        h4v oh; oh.x = (half_t)o.x; oh.y = (half_t)o.y; oh.z = (half_t)o.z; oh.w = (half_t)o.w;
        ((h4v*)Y)[(size_t)(n0 + r) * C4 + c4] = oh;
    }
}

// ---------------- weight transpose+convert + att convert ----------------

__global__ void wtrans(const float* __restrict__ c1l, const float* __restrict__ c1r,
                       const float* __restrict__ c2l, const float* __restrict__ c2r,
                       const float* __restrict__ ggl, const float* __restrict__ ggr,
                       const float* __restrict__ at1, const float* __restrict__ at2,
                       const float* __restrict__ atg, half_t* __restrict__ dst) {
    int idx = blockIdx.x * blockDim.x + threadIdx.x;
    if (idx >= 49440) return;
    if (idx >= 49152) {
        int j = idx - 49152;
        float v = (j < 128) ? at1[j] : (j < 256) ? at2[j - 128] : atg[j - 256];
        dst[idx] = (half_t)v;
        return;
    }
    const float* src; int K, loc;
    if (idx < 8192) {
        K = 32;
        if (idx < 4096) { src = c1l; loc = idx; } else { src = c1r; loc = idx - 4096; }
        int k = loc % K, c = loc / K;
        dst[idx] = (half_t)src[k * 128 + c];
    } else if (idx < 40960) {
        K = 128;
        if (idx < 24576) { src = c2l; loc = idx - 8192; } else { src = c2r; loc = idx - 24576; }
        int k = loc % K, c = loc / K;
        dst[idx] = (half_t)src[k * 128 + c];
    } else {
        K = 128;
        if (idx < 45056) { src = ggl; loc = idx - 40960; } else { src = ggr; loc = idx - 45056; }
        int k = loc % K, c = loc / K;
        dst[idx] = (half_t)src[k * 32 + c];
    }
}

// ---------------- MFMA dual GEMM ----------------

template <int K, int C1>
__global__ __launch_bounds__(256) void mfma_dual(
        const half_t* __restrict__ Xh,
        const half_t* __restrict__ W1t, const half_t* __restrict__ W2t,
        half_t* __restrict__ Y1, half_t* __restrict__ Y2, int Nr) {
    constexpr int KT = K / 32;
    constexpr int NBC = (2 * C1) / 64;
    int wave = threadIdx.x >> 6, lane = threadIdx.x & 63;
    int bCol = blockIdx.x % NBC;
    int bRow = blockIdx.x / NBC;
    int rowBase = bRow * 128 + wave * 32;
    int colBase = bCol * 64;
    int m = lane & 15, quad = lane >> 4;

    f4v acc[2][4] = {};

    const half_t* bptr[4];
#pragma unroll
    for (int nt = 0; nt < 4; ++nt) {
        int gc = colBase + nt * 16 + m;
        bptr[nt] = (gc < C1) ? (W1t + (size_t)gc * K) : (W2t + (size_t)(gc - C1) * K);
    }
    int r0 = rowBase + m, r1 = rowBase + 16 + m;
    int r0c = (r0 < Nr) ? r0 : (Nr - 1);
    int r1c = (r1 < Nr) ? r1 : (Nr - 1);
    const half_t* a0p = Xh + (size_t)r0c * K + quad * 8;
    const half_t* a1p = Xh + (size_t)r1c * K + quad * 8;

#pragma unroll
    for (int kk = 0; kk < KT; ++kk) {
        h8 a0 = *(const h8*)(a0p + kk * 32);
        h8 a1 = *(const h8*)(a1p + kk * 32);
#pragma unroll
        for (int nt = 0; nt < 4; ++nt) {
            h8 b = *(const h8*)(bptr[nt] + kk * 32 + quad * 8);
            acc[0][nt] = __builtin_amdgcn_mfma_f32_16x16x32_f16(a0, b, acc[0][nt], 0, 0, 0);
            acc[1][nt] = __builtin_amdgcn_mfma_f32_16x16x32_f16(a1, b, acc[1][nt], 0, 0, 0);
        }
    }

#pragma unroll
    for (int mt = 0; mt < 2; ++mt) {
#pragma unroll
        for (int nt = 0; nt < 4; ++nt) {
            int gc = colBase + nt * 16 + m;
            half_t* Y = (gc < C1) ? (Y1 + gc) : (Y2 + (gc - C1));
#pragma unroll
            for (int r = 0; r < 4; ++r) {
                int gr = rowBase + mt * 16 + quad * 4 + r;
                if (gr < Nr) Y[(size_t)gr * C1] = (half_t)acc[mt][nt][r];
            }
        }
    }
}

// ---------------- CSR construction ----------------
// Self-loops prefilled in scan_chunks; count_dst/fill_adj touch only E real edges.

__global__ void count_dst(const int* __restrict__ ei, int* __restrict__ counts, int E) {
    int e = blockIdx.x * blockDim.x + threadIdx.x;
    if (e >= E) return;
    atomicAdd(&counts[ei[E + e]], 1);
}

#define SCAN_CH 2048  // 256 threads x 8

__global__ void reduce_chunks(const int* __restrict__ counts, int* __restrict__ partial, int N) {
    __shared__ int sh[256];
    int t = threadIdx.x, base = blockIdx.x * SCAN_CH + t * 8;
    int s = 0;
    for (int j = 0; j < 8; ++j) if (base + j < N) s += counts[base + j] + 1;  // +1 self-loop
    sh[t] = s; __syncthreads();
    for (int off = 128; off >= 1; off >>= 1) {
        if (t < off) sh[t] += sh[t + off];
        __syncthreads();
    }
    if (t == 0) partial[blockIdx.x] = sh[0];
}

__global__ void scan_partials(int* __restrict__ partial, int nch) {
    if (threadIdx.x == 0 && blockIdx.x == 0) {
        int run = 0;
        for (int i = 0; i < nch; ++i) { int v = partial[i]; partial[i] = run; run += v; }
    }
}

// Writes offsets; seeds cursor past the self-loop; prefills the self-loop
// into adj; updates counts to true degree (incl. self-loop).
__global__ void scan_chunks(int* __restrict__ counts, const int* __restrict__ partial,
                            int* __restrict__ offsets, int* __restrict__ cursor,
                            int* __restrict__ adj, int N) {
    __shared__ int sh[256];
    int t = threadIdx.x, b = blockIdx.x, base = b * SCAN_CH + t * 8;
    int v[8], s = 0;
    for (int j = 0; j < 8; ++j) {
        v[j] = (base + j < N) ? (counts[base + j] + 1) : 0;
        s += v[j];
    }
    sh[t] = s; __syncthreads();
    for (int off = 1; off < 256; off <<= 1) {
        int x = (t >= off) ? sh[t - off] : 0;
        __syncthreads();
        sh[t] += x;
        __syncthreads();
    }
    int run = partial[b] + (t == 0 ? 0 : sh[t - 1]);
    for (int j = 0; j < 8; ++j) {
        if (base + j < N) {
            offsets[base + j] = run;
            adj[run] = base + j;       // self-loop first
            cursor[base + j] = run + 1;
            counts[base + j] = v[j];   // true degree (incl. self-loop)
        }
        run += v[j];
    }
}

// XCD-sliced adj scatter. R11 evidence: WRITE_SIZE 53.4 MB = 850K stores x 64 B
// -- every 4 B scatter paid a full-line write-back because writers of the same
// line sat on different (non-coherent) XCD L2s. Fix: slice the dst space 8 ways;
// block b handles slice b&7 (blockIdx%8 ~ XCD round-robin heuristic), so all
// stores to one adj region come from one XCD's L2 and write-combine there.
// Slice-groups stride over all E edges, filtering by dst (8x coalesced re-read
// of the dst array ~ 26 MB; cheap). Heuristic failure = perf-neutral, not wrong.
__global__ __launch_bounds__(256) void fill_adj_sliced(
        const int* __restrict__ ei, int* __restrict__ cursor,
        int* __restrict__ adj, int E, int sliceSz) {
    int slice = blockIdx.x & 7;
    int lo = slice * sliceSz, hi = lo + sliceSz;
    int nb = gridDim.x >> 3;          // blocks per slice
    int bi = blockIdx.x >> 3;
    int stride = nb * 256;
    for (int e = bi * 256 + threadIdx.x; e < E; e += stride) {
        int d = ei[E + e];
        if (d >= lo && d < hi) {
            int pos = atomicAdd(&cursor[d], 1);
            adj[pos] = ei[e];
        }
    }
}

// ---------------- fused GATv2, 8 dsts/wave, 8 lanes/dst ----------------

__global__ __launch_bounds__(256) void gat8_h4(
        const half_t* __restrict__ xl, const half_t* __restrict__ xr,
        const half_t* __restrict__ atth, const int* __restrict__ offsets,
        const int* __restrict__ counts, const int* __restrict__ adj,
        const float* __restrict__ bias, half_t* __restrict__ out, int N) {
    int wave = threadIdx.x >> 6, lane = threadIdx.x & 63;
    int g = lane >> 3, t = lane & 7;
    int d = blockIdx.x * 32 + wave * 8 + g;
    int dc = (d < N) ? d : (N - 1);
    int off = offsets[dc];
    int deg = (d < N) ? counts[dc] : 0;
    int dmax = deg;
    dmax = max(dmax, __shfl_xor(dmax, 8));
    dmax = max(dmax, __shfl_xor(dmax, 16));
    dmax = max(dmax, __shfl_xor(dmax, 32));

    const half_t* xrp = xr + (size_t)dc * 128 + t * 16;
    h8 xr_lo = *(const h8*)(xrp);
    h8 xr_hi = *(const h8*)(xrp + 8);
    H8u at_lo, at_hi;
    at_lo.v = *(const h8*)(atth + t * 16);
    at_hi.v = *(const h8*)(atth + t * 16 + 8);

    float acc[16];
#pragma unroll
    for (int j = 0; j < 16; ++j) acc[j] = 0.f;
    float lsum = 0.f;
    h8 c02;
#pragma unroll
    for (int j = 0; j < 8; ++j) c02[j] = (half_t)0.2f;

    for (int i = 0; i < dmax; ++i) {
        bool valid = (i < deg);
        int s = adj[off + (valid ? i : 0)];
        const half_t* xp = xl + (size_t)s * 128 + t * 16;
        H8u a_lo, a_hi;
        a_lo.v = *(const h8*)(xp);
        a_hi.v = *(const h8*)(xp + 8);
        h8 v_lo = a_lo.v + xr_lo;
        h8 v_hi = a_hi.v + xr_hi;
        H8u lk_lo, lk_hi;
        lk_lo.v = hmax8(v_lo, v_lo * c02);
        lk_hi.v = hmax8(v_hi, v_hi * c02);
        float p = 0.f;
#pragma unroll
        for (int j = 0; j < 4; ++j) p = dot2acc(lk_lo.h2[j], at_lo.h2[j], p);
#pragma unroll
        for (int j = 0; j < 4; ++j) p = dot2acc(lk_hi.h2[j], at_hi.h2[j], p);
        p += __shfl_xor(p, 1);                 // head-pair sum -> head score
        float w = valid ? __expf(p) : 0.f;
        lsum += w;
#pragma unroll
        for (int j = 0; j < 8; ++j) acc[j] += w * (float)a_lo.e[j];
#pragma unroll
        for (int j = 0; j < 8; ++j) acc[8 + j] += w * (float)a_hi.e[j];
    }

    if (d < N) {
        float inv = 1.f / lsum;
        H8u o_lo, o_hi;
#pragma unroll
        for (int j = 0; j < 8; ++j)
            o_lo.e[j] = (half_t)fmaxf(acc[j] * inv + bias[t * 16 + j], 0.f);
#pragma unroll
        for (int j = 0; j < 8; ++j)
            o_hi.e[j] = (half_t)fmaxf(acc[8 + j] * inv + bias[t * 16 + 8 + j], 0.f);
        half_t* op = out + (size_t)d * 128 + t * 16;
        *(h8*)(op) = o_lo.v;
        *(h8*)(op + 8) = o_hi.v;
    }
}

__global__ __launch_bounds__(256) void gat8_h1(
        const half_t* __restrict__ xl, const half_t* __restrict__ xr,
        const half_t* __restrict__ atth, const int* __restrict__ offsets,
        const int* __restrict__ counts, const int* __restrict__ adj,
        const float* __restrict__ bias, float* __restrict__ out, int N) {
    int wave = threadIdx.x >> 6, lane = threadIdx.x & 63;
    int g = lane >> 3, t = lane & 7;
    int d = blockIdx.x * 32 + wave * 8 + g;
    int dc = (d < N) ? d : (N - 1);
    int off = offsets[dc];
    int deg = (d < N) ? counts[dc] : 0;
    int dmax = deg;
    dmax = max(dmax, __shfl_xor(dmax, 8));
    dmax = max(dmax, __shfl_xor(dmax, 16));
    dmax = max(dmax, __shfl_xor(dmax, 32));

    h4v xr4 = *(const h4v*)(xr + (size_t)dc * 32 + t * 4);
    H4u at4; at4.v = *(const h4v*)(atth + t * 4);

    float acc[4] = {0.f, 0.f, 0.f, 0.f};
    float lsum = 0.f;
    h4v c02;
#pragma unroll
    for (int j = 0; j < 4; ++j) c02[j] = (half_t)0.2f;

    for (int i = 0; i < dmax; ++i) {
        bool valid = (i < deg);
        int s = adj[off + (valid ? i : 0)];
        H4u a; a.v = *(const h4v*)(xl + (size_t)s * 32 + t * 4);
        h4v v = a.v + xr4;
        H4u lk; lk.v = hmax4(v, v * c02);
        float p = dot2acc(lk.h2[0], at4.h2[0], 0.f);
        p = dot2acc(lk.h2[1], at4.h2[1], p);
        p += __shfl_xor(p, 1);
        p += __shfl_xor(p, 2);
        p += __shfl_xor(p, 4);
        float w = valid ? __expf(p) : 0.f;
        lsum += w;
#pragma unroll
        for (int j = 0; j < 4; ++j) acc[j] += w * (float)a.e[j];
    }

    if (d < N) {
        float inv = 1.f / lsum;
        float4 o;
        o.x = fmaxf(acc[0] * inv + bias[t * 4 + 0], 0.f);
        o.y = fmaxf(acc[1] * inv + bias[t * 4 + 1], 0.f);
        o.z = fmaxf(acc[2] * inv + bias[t * 4 + 2], 0.f);
        o.w = fmaxf(acc[3] * inv + bias[t * 4 + 3], 0.f);
        *(float4*)(out + (size_t)d * 32 + t * 4) = o;
    }
}

// ---------------- map branch ----------------

__global__ void map_sum_kernel(const float* __restrict__ lane_x, const float* __restrict__ map_W,
                               const float* __restrict__ map_b, float* __restrict__ sums, int M) {
    __shared__ float s[32];
    if (threadIdx.x < 32) s[threadIdx.x] = 0.f;
    __syncthreads();
    int t = blockIdx.x * blockDim.x + threadIdx.x;
    int nth = gridDim.x * blockDim.x;
    int c = t & 31;
    float w0 = map_W[c], w1 = map_W[32 + c], bb = map_b[c];
    float acc = 0.f;
    for (int m = t >> 5; m < M; m += nth >> 5) {
        float v = lane_x[(long)m * 2] * w0 + lane_x[(long)m * 2 + 1] * w1 + bb;
        acc += fmaxf(v, 0.f);
    }
    atomicAdd(&s[c], acc);
    __syncthreads();
    if (threadIdx.x < 32) atomicAdd(&sums[threadIdx.x], s[threadIdx.x]);
}

// ---------------- fused head ----------------

__global__ void head_kernel(const float* __restrict__ gf, const int* __restrict__ focal_idx,
                            const float* __restrict__ map_sums, int M,
                            const float* __restrict__ centerline, int L,
                            const float* __restrict__ cl_W, const float* __restrict__ cl_b,
                            const float* __restrict__ fc1_W, const float* __restrict__ fc1_b,
                            const float* __restrict__ fc2_W, const float* __restrict__ fc2_b,
                            const float* __restrict__ fco_W, const float* __restrict__ fco_b,
                            float* __restrict__ out) {
    int f = blockIdx.x;
    int lane = threadIdx.x;
    __shared__ float s_comb[96];
    __shared__ float s_h1[32];
    __shared__ float s_h2[16];
    __shared__ float s_cl[2];

    float c0 = 0.f, c1 = 0.f;
    if (lane < L) {
        c0 = centerline[((long)f * L + lane) * 2 + 0];
        c1 = centerline[((long)f * L + lane) * 2 + 1];
    }
    for (int off = 32; off >= 1; off >>= 1) {
        c0 += __shfl_down(c0, off);
        c1 += __shfl_down(c1, off);
    }
    if (lane == 0) { s_cl[0] = c0 / (float)L; s_cl[1] = c1 / (float)L; }
    __syncthreads();

    int fi = focal_idx[f];
    if (lane < 32) {
        s_comb[lane] = gf[(long)fi * 32 + lane];
        s_comb[32 + lane] = map_sums[lane] / (float)M;
        s_comb[64 + lane] = s_cl[0] * cl_W[lane] + s_cl[1] * cl_W[32 + lane] + cl_b[lane];
    }
    __syncthreads();

    if (lane < 32) {
        float acc = fc1_b[lane];
        for (int k = 0; k < 96; ++k) acc += s_comb[k] * fc1_W[k * 32 + lane];
        s_h1[lane] = fmaxf(acc, 0.f);
    }
    __syncthreads();

    if (lane < 16) {
        float acc = fc2_b[lane];
        for (int k = 0; k < 32; ++k) acc += s_h1[k] * fc2_W[k * 16 + lane];
        s_h2[lane] = fmaxf(acc, 0.f);
    }
    __syncthreads();

    if (lane < 60) {
        float acc = fco_b[lane];
        for (int k = 0; k < 16; ++k) acc += s_h2[k] * fco_W[k * 60 + lane];
        out[(long)f * 60 + lane] = acc;
    }
}

// ---------------- launch ----------------

extern "C" void kernel_launch(void* const* d_in, const int* in_sizes, int n_in,
                              void* d_out, int out_size, void* d_ws, size_t ws_size,
                              hipStream_t stream) {
    const float* x          = (const float*)d_in[0];
    const float* lane_x     = (const float*)d_in[1];
    const float* centerline = (const float*)d_in[2];
    const int*   ei         = (const int*)d_in[3];
    const int*   focal_idx  = (const int*)d_in[4];
    const float* emb_W = (const float*)d_in[5];
    const float* emb_b = (const float*)d_in[6];
    const float* c1_Wl = (const float*)d_in[7];
    const float* c1_Wr = (const float*)d_in[8];
    const float* c1_att = (const float*)d_in[9];
    const float* c1_b  = (const float*)d_in[10];
    const float* c2_Wl = (const float*)d_in[11];
    const float* c2_Wr = (const float*)d_in[12];
    const float* c2_att = (const float*)d_in[13];
    const float* c2_b  = (const float*)d_in[14];
    const float* map_W = (const float*)d_in[15];
    const float* map_b = (const float*)d_in[16];
    const float* gg_Wl = (const float*)d_in[17];
    const float* gg_Wr = (const float*)d_in[18];
    const float* gg_att = (const float*)d_in[19];
    const float* gg_b  = (const float*)d_in[20];
    const float* cl_W  = (const float*)d_in[21];
    const float* cl_b  = (const float*)d_in[22];
    const float* fc1_W = (const float*)d_in[23];
    const float* fc1_b = (const float*)d_in[24];
    const float* fc2_W = (const float*)d_in[25];
    const float* fc2_b = (const float*)d_in[26];
    const float* fco_W = (const float*)d_in[27];
    const float* fco_b = (const float*)d_in[28];

    const int N = in_sizes[0] / 60;
    const int M = in_sizes[1] / 2;
    const int F = in_sizes[4];
    const int L = in_sizes[2] / (F * 2);
    const int E = in_sizes[3] / 2;
    const int Etot = E + N;

    // Workspace layout:
    half_t* Xl_h = (half_t*)d_ws;                    // N*128
    half_t* Xr_h = Xl_h + (size_t)N * 128;           // N*128
    half_t* H0_h = Xr_h + (size_t)N * 128;           // N*32
    half_t* H1_h = H0_h + (size_t)N * 32;            // N*128
    half_t* AF_h = H1_h + (size_t)N * 128;           // N*128
    float*  GF_f = (float*)(AF_h + (size_t)N * 128); // N*32 f32
    half_t* Wt   = (half_t*)(GF_f + (size_t)N * 32); // 49440 halfs
    int* counts  = (int*)(Wt + 49440);               // N
    int* offsets = counts + N;                        // N
    int* cursor  = offsets + N;                       // N
    int* adj     = cursor + N;                        // Etot
    float* MAPS  = (float*)(adj + Etot);              // 32
    int* partial = (int*)(MAPS + 32);                 // nch

    half_t* c1Wlt = Wt + 0;
    half_t* c1Wrt = Wt + 4096;
    half_t* c2Wlt = Wt + 8192;
    half_t* c2Wrt = Wt + 24576;
    half_t* ggWlt = Wt + 40960;
    half_t* ggWrt = Wt + 45056;
    half_t* att1h = Wt + 49152;
    half_t* att2h = Wt + 49280;
    half_t* attgh = Wt + 49408;

    const int BS = 256;
    const int nch = cdiv(N, SCAN_CH);
    const int rowBlocks = cdiv(N, 128);
    const int sliceSz = cdiv(N, 8);

    // ---- CSR build (self-loops prefilled in scan_chunks; XCD-sliced scatter) ----
    hipMemsetAsync(counts, 0, (size_t)N * sizeof(int), stream);
    count_dst<<<cdiv(E, BS), BS, 0, stream>>>(ei, counts, E);
    reduce_chunks<<<nch, 256, 0, stream>>>(counts, partial, N);
    scan_partials<<<1, 64, 0, stream>>>(partial, nch);
    scan_chunks<<<nch, 256, 0, stream>>>(counts, partial, offsets, cursor, adj, N);
    fill_adj_sliced<<<8 * 104, 256, 0, stream>>>(ei, cursor, adj, E, sliceSz);

    // ---- weights + att -> f16 ----
    wtrans<<<cdiv(49440, BS), BS, 0, stream>>>(c1_Wl, c1_Wr, c2_Wl, c2_Wr, gg_Wl, gg_Wr,
                                               c1_att, c2_att, gg_att, Wt);

    // ---- h0 = relu(x @ emb_W + emb_b) -> H0_h ----
    gemm_t_h<15, 8, 4><<<cdiv((long)(N / 4) * 8, BS), BS, 0, stream>>>(x, emb_W, emb_b, H0_h, N, 1);

    // ---- layer 1 (H=4) ----
    mfma_dual<32, 128><<<rowBlocks * 4, 256, 0, stream>>>(H0_h, c1Wlt, c1Wrt, Xl_h, Xr_h, N);
    gat8_h4<<<cdiv(N, 32), 256, 0, stream>>>(Xl_h, Xr_h, att1h, offsets, counts, adj, c1_b, H1_h, N);

    // ---- layer 2 (H=4) ----
    mfma_dual<128, 128><<<rowBlocks * 4, 256, 0, stream>>>(H1_h, c2Wlt, c2Wrt, Xl_h, Xr_h, N);
    gat8_h4<<<cdiv(N, 32), 256, 0, stream>>>(Xl_h, Xr_h, att2h, offsets, counts, adj, c2_b, AF_h, N);

    // ---- global graph (H=1) ----
    mfma_dual<128, 32><<<rowBlocks * 1, 256, 0, stream>>>(AF_h, ggWlt, ggWrt, Xl_h, Xr_h, N);
    gat8_h1<<<cdiv(N, 32), 256, 0, stream>>>(Xl_h, Xr_h, attgh, offsets, counts, adj, gg_b, GF_f, N);

    // ---- map branch ----
    hipMemsetAsync(MAPS, 0, 32 * sizeof(float), stream);
    map_sum_kernel<<<64, BS, 0, stream>>>(lane_x, map_W, map_b, MAPS, M);

    // ---- fused head ----
    head_kernel<<<F, 64, 0, stream>>>(GF_f, focal_idx, MAPS, M, centerline, L,
                                      cl_W, cl_b, fc1_W, fc1_b, fc2_W, fc2_b,
                                      fco_W, fco_b, (float*)d_out);
}

// Round 13
// 386.648 us; speedup vs baseline: 1.7391x; 1.0335x over previous
//
#include <hip/hip_runtime.h>
#include <hip/hip_bf16.h>
#include <hip/hip_fp16.h>

typedef _Float16 half_t;
typedef _Float16 h8 __attribute__((ext_vector_type(8)));
typedef _Float16 h4v __attribute__((ext_vector_type(4)));
typedef _Float16 h2v __attribute__((ext_vector_type(2)));
typedef float f4v __attribute__((ext_vector_type(4)));

union H8u { h8 v; h2v h2[4]; _Float16 e[8]; };
union H4u { h4v v; h2v h2[2]; _Float16 e[4]; };

static inline int cdiv(long a, long b) { return (int)((a + b - 1) / b); }

__device__ __forceinline__ void fma4(float4& a, float s, const float4& w) {
    a.x += s * w.x; a.y += s * w.y; a.z += s * w.z; a.w += s * w.w;
}

__device__ __forceinline__ h8 hmax8(h8 a, h8 b) {
#if __has_builtin(__builtin_elementwise_max)
    return __builtin_elementwise_max(a, b);
#else
    h8 r;
#pragma unroll
    for (int j = 0; j < 8; ++j) r[j] = (a[j] > b[j]) ? a[j] : b[j];
    return r;
#endif
}
__device__ __forceinline__ h4v hmax4(h4v a, h4v b) {
#if __has_builtin(__builtin_elementwise_max)
    return __builtin_elementwise_max(a, b);
#else
    h4v r;
#pragma unroll
    for (int j = 0; j < 4; ++j) r[j] = (a[j] > b[j]) ? a[j] : b[j];
    return r;
#endif
}

__device__ __forceinline__ float dot2acc(h2v a, h2v b, float c) {
#if __has_builtin(__builtin_amdgcn_fdot2)
    return __builtin_amdgcn_fdot2(a, b, c, false);
#else
    return c + (float)a.x * (float)b.x + (float)a.y * (float)b.y;
#endif
}

// ---------------- emb GEMM (fp32 compute, fp16 out) ----------------

template <int K4, int C4, int R>
__global__ __launch_bounds__(256) void gemm_t_h(
        const float* __restrict__ X, const float* __restrict__ W,
        const float* __restrict__ bias, half_t* __restrict__ Y,
        int Nr, int relu) {
    int idx = blockIdx.x * blockDim.x + threadIdx.x;
    int total = (Nr / R) * C4;
    if (idx >= total) return;
    int c4 = idx % C4;
    int n0 = (idx / C4) * R;
    const float4* __restrict__ Wv = (const float4*)W;
    const float4* __restrict__ Xv = (const float4*)X;
    float4 acc[R];
    float4 binit = bias ? ((const float4*)bias)[c4] : make_float4(0.f, 0.f, 0.f, 0.f);
#pragma unroll
    for (int r = 0; r < R; ++r) acc[r] = binit;
#pragma unroll 4
    for (int k4 = 0; k4 < K4; ++k4) {
        float4 w0 = Wv[(size_t)(4 * k4 + 0) * C4 + c4];
        float4 w1 = Wv[(size_t)(4 * k4 + 1) * C4 + c4];
        float4 w2 = Wv[(size_t)(4 * k4 + 2) * C4 + c4];
        float4 w3 = Wv[(size_t)(4 * k4 + 3) * C4 + c4];
#pragma unroll
        for (int r = 0; r < R; ++r) {
            float4 xv = Xv[(size_t)(n0 + r) * K4 + k4];
            fma4(acc[r], xv.x, w0); fma4(acc[r], xv.y, w1);
            fma4(acc[r], xv.z, w2); fma4(acc[r], xv.w, w3);
        }
    }
#pragma unroll
    for (int r = 0; r < R; ++r) {
        float4 o = acc[r];
        if (relu) {
            o.x = fmaxf(o.x, 0.f); o.y = fmaxf(o.y, 0.f);
            o.z = fmaxf(o.z, 0.f); o.w = fmaxf(o.w, 0.f);
        }
        h4v oh; oh.x = (half_t)o.x; oh.y = (half_t)o.y; oh.z = (half_t)o.z; oh.w = (half_t)o.w;
        ((h4v*)Y)[(size_t)(n0 + r) * C4 + c4] = oh;
    }
}

// ---------------- weight transpose+convert + att convert ----------------

__global__ void wtrans(const float* __restrict__ c1l, const float* __restrict__ c1r,
                       const float* __restrict__ c2l, const float* __restrict__ c2r,
                       const float* __restrict__ ggl, const float* __restrict__ ggr,
                       const float* __restrict__ at1, const float* __restrict__ at2,
                       const float* __restrict__ atg, half_t* __restrict__ dst) {
    int idx = blockIdx.x * blockDim.x + threadIdx.x;
    if (idx >= 49440) return;
    if (idx >= 49152) {
        int j = idx - 49152;
        float v = (j < 128) ? at1[j] : (j < 256) ? at2[j - 128] : atg[j - 256];
        dst[idx] = (half_t)v;
        return;
    }
    const float* src; int K, loc;
    if (idx < 8192) {
        K = 32;
        if (idx < 4096) { src = c1l; loc = idx; } else { src = c1r; loc = idx - 4096; }
        int k = loc % K, c = loc / K;
        dst[idx] = (half_t)src[k * 128 + c];
    } else if (idx < 40960) {
        K = 128;
        if (idx < 24576) { src = c2l; loc = idx - 8192; } else { src = c2r; loc = idx - 24576; }
        int k = loc % K, c = loc / K;
        dst[idx] = (half_t)src[k * 128 + c];
    } else {
        K = 128;
        if (idx < 45056) { src = ggl; loc = idx - 40960; } else { src = ggr; loc = idx - 45056; }
        int k = loc % K, c = loc / K;
        dst[idx] = (half_t)src[k * 32 + c];
    }
}

// ---------------- MFMA dual GEMM ----------------

template <int K, int C1>
__global__ __launch_bounds__(256) void mfma_dual(
        const half_t* __restrict__ Xh,
        const half_t* __restrict__ W1t, const half_t* __restrict__ W2t,
        half_t* __restrict__ Y1, half_t* __restrict__ Y2, int Nr) {
    constexpr int KT = K / 32;
    constexpr int NBC = (2 * C1) / 64;
    int wave = threadIdx.x >> 6, lane = threadIdx.x & 63;
    int bCol = blockIdx.x % NBC;
    int bRow = blockIdx.x / NBC;
    int rowBase = bRow * 128 + wave * 32;
    int colBase = bCol * 64;
    int m = lane & 15, quad = lane >> 4;

    f4v acc[2][4] = {};

    const half_t* bptr[4];
#pragma unroll
    for (int nt = 0; nt < 4; ++nt) {
        int gc = colBase + nt * 16 + m;
        bptr[nt] = (gc < C1) ? (W1t + (size_t)gc * K) : (W2t + (size_t)(gc - C1) * K);
    }
    int r0 = rowBase + m, r1 = rowBase + 16 + m;
    int r0c = (r0 < Nr) ? r0 : (Nr - 1);
    int r1c = (r1 < Nr) ? r1 : (Nr - 1);
    const half_t* a0p = Xh + (size_t)r0c * K + quad * 8;
    const half_t* a1p = Xh + (size_t)r1c * K + quad * 8;

#pragma unroll
    for (int kk = 0; kk < KT; ++kk) {
        h8 a0 = *(const h8*)(a0p + kk * 32);
        h8 a1 = *(const h8*)(a1p + kk * 32);
#pragma unroll
        for (int nt = 0; nt < 4; ++nt) {
            h8 b = *(const h8*)(bptr[nt] + kk * 32 + quad * 8);
            acc[0][nt] = __builtin_amdgcn_mfma_f32_16x16x32_f16(a0, b, acc[0][nt], 0, 0, 0);
            acc[1][nt] = __builtin_amdgcn_mfma_f32_16x16x32_f16(a1, b, acc[1][nt], 0, 0, 0);
        }
    }

#pragma unroll
    for (int mt = 0; mt < 2; ++mt) {
#pragma unroll
        for (int nt = 0; nt < 4; ++nt) {
            int gc = colBase + nt * 16 + m;
            half_t* Y = (gc < C1) ? (Y1 + gc) : (Y2 + (gc - C1));
#pragma unroll
            for (int r = 0; r < 4; ++r) {
                int gr = rowBase + mt * 16 + quad * 4 + r;
                if (gr < Nr) Y[(size_t)gr * C1] = (half_t)acc[mt][nt][r];
            }
        }
    }
}

// ---------------- CSR construction ----------------
// Self-loops prefilled in scan_chunks; count_dst/fill_adj touch only E real edges.

__global__ void count_dst(const int* __restrict__ ei, int* __restrict__ counts, int E) {
    int e = blockIdx.x * blockDim.x + threadIdx.x;
    if (e >= E) return;
    atomicAdd(&counts[ei[E + e]], 1);
}

#define SCAN_CH 2048  // 256 threads x 8

__global__ void reduce_chunks(const int* __restrict__ counts, int* __restrict__ partial, int N) {
    __shared__ int sh[256];
    int t = threadIdx.x, base = blockIdx.x * SCAN_CH + t * 8;
    int s = 0;
    for (int j = 0; j < 8; ++j) if (base + j < N) s += counts[base + j] + 1;  // +1 self-loop
    sh[t] = s; __syncthreads();
    for (int off = 128; off >= 1; off >>= 1) {
        if (t < off) sh[t] += sh[t + off];
        __syncthreads();
    }
    if (t == 0) partial[blockIdx.x] = sh[0];
}

__global__ void scan_partials(int* __restrict__ partial, int nch) {
    if (threadIdx.x == 0 && blockIdx.x == 0) {
        int run = 0;
        for (int i = 0; i < nch; ++i) { int v = partial[i]; partial[i] = run; run += v; }
    }
}

// Writes offsets; seeds cursor past the self-loop; prefills the self-loop
// into adj; updates counts to true degree (incl. self-loop).
__global__ void scan_chunks(int* __restrict__ counts, const int* __restrict__ partial,
                            int* __restrict__ offsets, int* __restrict__ cursor,
                            int* __restrict__ adj, int N) {
    __shared__ int sh[256];
    int t = threadIdx.x, b = blockIdx.x, base = b * SCAN_CH + t * 8;
    int v[8], s = 0;
    for (int j = 0; j < 8; ++j) {
        v[j] = (base + j < N) ? (counts[base + j] + 1) : 0;
        s += v[j];
    }
    sh[t] = s; __syncthreads();
    for (int off = 1; off < 256; off <<= 1) {
        int x = (t >= off) ? sh[t - off] : 0;
        __syncthreads();
        sh[t] += x;
        __syncthreads();
    }
    int run = partial[b] + (t == 0 ? 0 : sh[t - 1]);
    for (int j = 0; j < 8; ++j) {
        if (base + j < N) {
            offsets[base + j] = run;
            adj[run] = base + j;       // self-loop first
            cursor[base + j] = run + 1;
            counts[base + j] = v[j];   // true degree (incl. self-loop)
        }
        run += v[j];
    }
}

// XCD-sliced adj scatter (verified R12: removed fill_adj's 53 MB write-back
// amplification). Block b handles dst slice b&7 (blockIdx%8 ~ XCD round-robin),
// so all stores to one adj region write-combine in one XCD's L2.
__global__ __launch_bounds__(256) void fill_adj_sliced(
        const int* __restrict__ ei, int* __restrict__ cursor,
        int* __restrict__ adj, int E, int sliceSz) {
    int slice = blockIdx.x & 7;
    int lo = slice * sliceSz, hi = lo + sliceSz;
    int nb = gridDim.x >> 3;          // blocks per slice
    int bi = blockIdx.x >> 3;
    int stride = nb * 256;
    for (int e = bi * 256 + threadIdx.x; e < E; e += stride) {
        int d = ei[E + e];
        if (d >= lo && d < hi) {
            int pos = atomicAdd(&cursor[d], 1);
            adj[pos] = ei[e];
        }
    }
}

// ---------------- fused GATv2, 8 dsts/wave, 8 lanes/dst, unroll x2 ----------------
// R12: 43 µs, VALUBusy 39%, occ 43% -> latency-bound with 1 edge in flight per
// group. Unroll x2 = two independent gather+score chains per group.

__global__ __launch_bounds__(256) void gat8_h4(
        const half_t* __restrict__ xl, const half_t* __restrict__ xr,
        const half_t* __restrict__ atth, const int* __restrict__ offsets,
        const int* __restrict__ counts, const int* __restrict__ adj,
        const float* __restrict__ bias, half_t* __restrict__ out, int N) {
    int wave = threadIdx.x >> 6, lane = threadIdx.x & 63;
    int g = lane >> 3, t = lane & 7;
    int d = blockIdx.x * 32 + wave * 8 + g;
    int dc = (d < N) ? d : (N - 1);
    int off = offsets[dc];
    int deg = (d < N) ? counts[dc] : 0;
    int dmax = deg;
    dmax = max(dmax, __shfl_xor(dmax, 8));
    dmax = max(dmax, __shfl_xor(dmax, 16));
    dmax = max(dmax, __shfl_xor(dmax, 32));

    const half_t* xrp = xr + (size_t)dc * 128 + t * 16;
    h8 xr_lo = *(const h8*)(xrp);
    h8 xr_hi = *(const h8*)(xrp + 8);
    H8u at_lo, at_hi;
    at_lo.v = *(const h8*)(atth + t * 16);
    at_hi.v = *(const h8*)(atth + t * 16 + 8);

    float acc[16];
#pragma unroll
    for (int j = 0; j < 16; ++j) acc[j] = 0.f;
    float lsum = 0.f;
    h8 c02;
#pragma unroll
    for (int j = 0; j < 8; ++j) c02[j] = (half_t)0.2f;

    int i = 0;
    for (; i + 2 <= dmax; i += 2) {
        bool va = (i < deg), vb = (i + 1 < deg);
        int sa = adj[off + (va ? i : 0)];
        int sb = adj[off + (vb ? i + 1 : 0)];
        const half_t* xpa = xl + (size_t)sa * 128 + t * 16;
        const half_t* xpb = xl + (size_t)sb * 128 + t * 16;
        H8u aa_lo, aa_hi, ab_lo, ab_hi;
        aa_lo.v = *(const h8*)(xpa);
        aa_hi.v = *(const h8*)(xpa + 8);
        ab_lo.v = *(const h8*)(xpb);
        ab_hi.v = *(const h8*)(xpb + 8);

        h8 va_lo = aa_lo.v + xr_lo, va_hi = aa_hi.v + xr_hi;
        h8 vb_lo = ab_lo.v + xr_lo, vb_hi = ab_hi.v + xr_hi;
        H8u la_lo, la_hi, lb_lo, lb_hi;
        la_lo.v = hmax8(va_lo, va_lo * c02);
        la_hi.v = hmax8(va_hi, va_hi * c02);
        lb_lo.v = hmax8(vb_lo, vb_lo * c02);
        lb_hi.v = hmax8(vb_hi, vb_hi * c02);

        float pa = 0.f, pb = 0.f;
#pragma unroll
        for (int j = 0; j < 4; ++j) {
            pa = dot2acc(la_lo.h2[j], at_lo.h2[j], pa);
            pb = dot2acc(lb_lo.h2[j], at_lo.h2[j], pb);
        }
#pragma unroll
        for (int j = 0; j < 4; ++j) {
            pa = dot2acc(la_hi.h2[j], at_hi.h2[j], pa);
            pb = dot2acc(lb_hi.h2[j], at_hi.h2[j], pb);
        }
        pa += __shfl_xor(pa, 1);
        pb += __shfl_xor(pb, 1);
        float wa = va ? __expf(pa) : 0.f;
        float wb = vb ? __expf(pb) : 0.f;
        lsum += wa + wb;
#pragma unroll
        for (int j = 0; j < 8; ++j)
            acc[j] += wa * (float)aa_lo.e[j] + wb * (float)ab_lo.e[j];
#pragma unroll
        for (int j = 0; j < 8; ++j)
            acc[8 + j] += wa * (float)aa_hi.e[j] + wb * (float)ab_hi.e[j];
    }
    for (; i < dmax; ++i) {
        bool valid = (i < deg);
        int s = adj[off + (valid ? i : 0)];
        const half_t* xp = xl + (size_t)s * 128 + t * 16;
        H8u a_lo, a_hi;
        a_lo.v = *(const h8*)(xp);
        a_hi.v = *(const h8*)(xp + 8);
        h8 v_lo = a_lo.v + xr_lo;
        h8 v_hi = a_hi.v + xr_hi;
        H8u lk_lo, lk_hi;
        lk_lo.v = hmax8(v_lo, v_lo * c02);
        lk_hi.v = hmax8(v_hi, v_hi * c02);
        float p = 0.f;
#pragma unroll
        for (int j = 0; j < 4; ++j) p = dot2acc(lk_lo.h2[j], at_lo.h2[j], p);
#pragma unroll
        for (int j = 0; j < 4; ++j) p = dot2acc(lk_hi.h2[j], at_hi.h2[j], p);
        p += __shfl_xor(p, 1);
        float w = valid ? __expf(p) : 0.f;
        lsum += w;
#pragma unroll
        for (int j = 0; j < 8; ++j) acc[j] += w * (float)a_lo.e[j];
#pragma unroll
        for (int j = 0; j < 8; ++j) acc[8 + j] += w * (float)a_hi.e[j];
    }

    if (d < N) {
        float inv = 1.f / lsum;
        H8u o_lo, o_hi;
#pragma unroll
        for (int j = 0; j < 8; ++j)
            o_lo.e[j] = (half_t)fmaxf(acc[j] * inv + bias[t * 16 + j], 0.f);
#pragma unroll
        for (int j = 0; j < 8; ++j)
            o_hi.e[j] = (half_t)fmaxf(acc[8 + j] * inv + bias[t * 16 + 8 + j], 0.f);
        half_t* op = out + (size_t)d * 128 + t * 16;
        *(h8*)(op) = o_lo.v;
        *(h8*)(op + 8) = o_hi.v;
    }
}

__global__ __launch_bounds__(256) void gat8_h1(
        const half_t* __restrict__ xl, const half_t* __restrict__ xr,
        const half_t* __restrict__ atth, const int* __restrict__ offsets,
        const int* __restrict__ counts, const int* __restrict__ adj,
        const float* __restrict__ bias, float* __restrict__ out, int N) {
    int wave = threadIdx.x >> 6, lane = threadIdx.x & 63;
    int g = lane >> 3, t = lane & 7;
    int d = blockIdx.x * 32 + wave * 8 + g;
    int dc = (d < N) ? d : (N - 1);
    int off = offsets[dc];
    int deg = (d < N) ? counts[dc] : 0;
    int dmax = deg;
    dmax = max(dmax, __shfl_xor(dmax, 8));
    dmax = max(dmax, __shfl_xor(dmax, 16));
    dmax = max(dmax, __shfl_xor(dmax, 32));

    h4v xr4 = *(const h4v*)(xr + (size_t)dc * 32 + t * 4);
    H4u at4; at4.v = *(const h4v*)(atth + t * 4);

    float acc[4] = {0.f, 0.f, 0.f, 0.f};
    float lsum = 0.f;
    h4v c02;
#pragma unroll
    for (int j = 0; j < 4; ++j) c02[j] = (half_t)0.2f;

    int i = 0;
    for (; i + 2 <= dmax; i += 2) {
        bool va = (i < deg), vb = (i + 1 < deg);
        int sa = adj[off + (va ? i : 0)];
        int sb = adj[off + (vb ? i + 1 : 0)];
        H4u a, b;
        a.v = *(const h4v*)(xl + (size_t)sa * 32 + t * 4);
        b.v = *(const h4v*)(xl + (size_t)sb * 32 + t * 4);
        h4v vva = a.v + xr4, vvb = b.v + xr4;
        H4u la, lb;
        la.v = hmax4(vva, vva * c02);
        lb.v = hmax4(vvb, vvb * c02);
        float pa = dot2acc(la.h2[0], at4.h2[0], 0.f);
        float pb = dot2acc(lb.h2[0], at4.h2[0], 0.f);
        pa = dot2acc(la.h2[1], at4.h2[1], pa);
        pb = dot2acc(lb.h2[1], at4.h2[1], pb);
        pa += __shfl_xor(pa, 1); pb += __shfl_xor(pb, 1);
        pa += __shfl_xor(pa, 2); pb += __shfl_xor(pb, 2);
        pa += __shfl_xor(pa, 4); pb += __shfl_xor(pb, 4);
        float wa = va ? __expf(pa) : 0.f;
        float wb = vb ? __expf(pb) : 0.f;
        lsum += wa + wb;
#pragma unroll
        for (int j = 0; j < 4; ++j)
            acc[j] += wa * (float)a.e[j] + wb * (float)b.e[j];
    }
    for (; i < dmax; ++i) {
        bool valid = (i < deg);
        int s = adj[off + (valid ? i : 0)];
        H4u a; a.v = *(const h4v*)(xl + (size_t)s * 32 + t * 4);
        h4v v = a.v + xr4;
        H4u lk; lk.v = hmax4(v, v * c02);
        float p = dot2acc(lk.h2[0], at4.h2[0], 0.f);
        p = dot2acc(lk.h2[1], at4.h2[1], p);
        p += __shfl_xor(p, 1);
        p += __shfl_xor(p, 2);
        p += __shfl_xor(p, 4);
        float w = valid ? __expf(p) : 0.f;
        lsum += w;
#pragma unroll
        for (int j = 0; j < 4; ++j) acc[j] += w * (float)a.e[j];
    }

    if (d < N) {
        float inv = 1.f / lsum;
        float4 o;
        o.x = fmaxf(acc[0] * inv + bias[t * 4 + 0], 0.f);
        o.y = fmaxf(acc[1] * inv + bias[t * 4 + 1], 0.f);
        o.z = fmaxf(acc[2] * inv + bias[t * 4 + 2], 0.f);
        o.w = fmaxf(acc[3] * inv + bias[t * 4 + 3], 0.f);
        *(float4*)(out + (size_t)d * 32 + t * 4) = o;
    }
}

// ---------------- map branch ----------------

__global__ void map_sum_kernel(const float* __restrict__ lane_x, const float* __restrict__ map_W,
                               const float* __restrict__ map_b, float* __restrict__ sums, int M) {
    __shared__ float s[32];
    if (threadIdx.x < 32) s[threadIdx.x] = 0.f;
    __syncthreads();
    int t = blockIdx.x * blockDim.x + threadIdx.x;
    int nth = gridDim.x * blockDim.x;
    int c = t & 31;
    float w0 = map_W[c], w1 = map_W[32 + c], bb = map_b[c];
    float acc = 0.f;
    for (int m = t >> 5; m < M; m += nth >> 5) {
        float v = lane_x[(long)m * 2] * w0 + lane_x[(long)m * 2 + 1] * w1 + bb;
        acc += fmaxf(v, 0.f);
    }
    atomicAdd(&s[c], acc);
    __syncthreads();
    if (threadIdx.x < 32) atomicAdd(&sums[threadIdx.x], s[threadIdx.x]);
}

// ---------------- fused head ----------------

__global__ void head_kernel(const float* __restrict__ gf, const int* __restrict__ focal_idx,
                            const float* __restrict__ map_sums, int M,
                            const float* __restrict__ centerline, int L,
                            const float* __restrict__ cl_W, const float* __restrict__ cl_b,
                            const float* __restrict__ fc1_W, const float* __restrict__ fc1_b,
                            const float* __restrict__ fc2_W, const float* __restrict__ fc2_b,
                            const float* __restrict__ fco_W, const float* __restrict__ fco_b,
                            float* __restrict__ out) {
    int f = blockIdx.x;
    int lane = threadIdx.x;
    __shared__ float s_comb[96];
    __shared__ float s_h1[32];
    __shared__ float s_h2[16];
    __shared__ float s_cl[2];

    float c0 = 0.f, c1 = 0.f;
    if (lane < L) {
        c0 = centerline[((long)f * L + lane) * 2 + 0];
        c1 = centerline[((long)f * L + lane) * 2 + 1];
    }
    for (int off = 32; off >= 1; off >>= 1) {
        c0 += __shfl_down(c0, off);
        c1 += __shfl_down(c1, off);
    }
    if (lane == 0) { s_cl[0] = c0 / (float)L; s_cl[1] = c1 / (float)L; }
    __syncthreads();

    int fi = focal_idx[f];
    if (lane < 32) {
        s_comb[lane] = gf[(long)fi * 32 + lane];
        s_comb[32 + lane] = map_sums[lane] / (float)M;
        s_comb[64 + lane] = s_cl[0] * cl_W[lane] + s_cl[1] * cl_W[32 + lane] + cl_b[lane];
    }
    __syncthreads();

    if (lane < 32) {
        float acc = fc1_b[lane];
        for (int k = 0; k < 96; ++k) acc += s_comb[k] * fc1_W[k * 32 + lane];
        s_h1[lane] = fmaxf(acc, 0.f);
    }
    __syncthreads();

    if (lane < 16) {
        float acc = fc2_b[lane];
        for (int k = 0; k < 32; ++k) acc += s_h1[k] * fc2_W[k * 16 + lane];
        s_h2[lane] = fmaxf(acc, 0.f);
    }
    __syncthreads();

    if (lane < 60) {
        float acc = fco_b[lane];
        for (int k = 0; k < 16; ++k) acc += s_h2[k] * fco_W[k * 60 + lane];
        out[(long)f * 60 + lane] = acc;
    }
}

// ---------------- launch ----------------

extern "C" void kernel_launch(void* const* d_in, const int* in_sizes, int n_in,
                              void* d_out, int out_size, void* d_ws, size_t ws_size,
                              hipStream_t stream) {
    const float* x          = (const float*)d_in[0];
    const float* lane_x     = (const float*)d_in[1];
    const float* centerline = (const float*)d_in[2];
    const int*   ei         = (const int*)d_in[3];
    const int*   focal_idx  = (const int*)d_in[4];
    const float* emb_W = (const float*)d_in[5];
    const float* emb_b = (const float*)d_in[6];
    const float* c1_Wl = (const float*)d_in[7];
    const float* c1_Wr = (const float*)d_in[8];
    const float* c1_att = (const float*)d_in[9];
    const float* c1_b  = (const float*)d_in[10];
    const float* c2_Wl = (const float*)d_in[11];
    const float* c2_Wr = (const float*)d_in[12];
    const float* c2_att = (const float*)d_in[13];
    const float* c2_b  = (const float*)d_in[14];
    const float* map_W = (const float*)d_in[15];
    const float* map_b = (const float*)d_in[16];
    const float* gg_Wl = (const float*)d_in[17];
    const float* gg_Wr = (const float*)d_in[18];
    const float* gg_att = (const float*)d_in[19];
    const float* gg_b  = (const float*)d_in[20];
    const float* cl_W  = (const float*)d_in[21];
    const float* cl_b  = (const float*)d_in[22];
    const float* fc1_W = (const float*)d_in[23];
    const float* fc1_b = (const float*)d_in[24];
    const float* fc2_W = (const float*)d_in[25];
    const float* fc2_b = (const float*)d_in[26];
    const float* fco_W = (const float*)d_in[27];
    const float* fco_b = (const float*)d_in[28];

    const int N = in_sizes[0] / 60;
    const int M = in_sizes[1] / 2;
    const int F = in_sizes[4];
    const int L = in_sizes[2] / (F * 2);
    const int E = in_sizes[3] / 2;
    const int Etot = E + N;

    // Workspace layout:
    half_t* Xl_h = (half_t*)d_ws;                    // N*128
    half_t* Xr_h = Xl_h + (size_t)N * 128;           // N*128
    half_t* H0_h = Xr_h + (size_t)N * 128;           // N*32
    half_t* H1_h = H0_h + (size_t)N * 32;            // N*128
    half_t* AF_h = H1_h + (size_t)N * 128;           // N*128
    float*  GF_f = (float*)(AF_h + (size_t)N * 128); // N*32 f32
    half_t* Wt   = (half_t*)(GF_f + (size_t)N * 32); // 49440 halfs
    int* counts  = (int*)(Wt + 49440);               // N
    int* offsets = counts + N;                        // N
    int* cursor  = offsets + N;                       // N
    int* adj     = cursor + N;                        // Etot
    float* MAPS  = (float*)(adj + Etot);              // 32
    int* partial = (int*)(MAPS + 32);                 // nch

    half_t* c1Wlt = Wt + 0;
    half_t* c1Wrt = Wt + 4096;
    half_t* c2Wlt = Wt + 8192;
    half_t* c2Wrt = Wt + 24576;
    half_t* ggWlt = Wt + 40960;
    half_t* ggWrt = Wt + 45056;
    half_t* att1h = Wt + 49152;
    half_t* att2h = Wt + 49280;
    half_t* attgh = Wt + 49408;

    const int BS = 256;
    const int nch = cdiv(N, SCAN_CH);
    const int rowBlocks = cdiv(N, 128);
    const int sliceSz = cdiv(N, 8);

    // ---- CSR build (self-loops prefilled in scan_chunks; XCD-sliced scatter) ----
    hipMemsetAsync(counts, 0, (size_t)N * sizeof(int), stream);
    count_dst<<<cdiv(E, BS), BS, 0, stream>>>(ei, counts, E);
    reduce_chunks<<<nch, 256, 0, stream>>>(counts, partial, N);
    scan_partials<<<1, 64, 0, stream>>>(partial, nch);
    scan_chunks<<<nch, 256, 0, stream>>>(counts, partial, offsets, cursor, adj, N);
    fill_adj_sliced<<<8 * 104, 256, 0, stream>>>(ei, cursor, adj, E, sliceSz);

    // ---- weights + att -> f16 ----
    wtrans<<<cdiv(49440, BS), BS, 0, stream>>>(c1_Wl, c1_Wr, c2_Wl, c2_Wr, gg_Wl, gg_Wr,
                                               c1_att, c2_att, gg_att, Wt);

    // ---- h0 = relu(x @ emb_W + emb_b) -> H0_h ----
    gemm_t_h<15, 8, 4><<<cdiv((long)(N / 4) * 8, BS), BS, 0, stream>>>(x, emb_W, emb_b, H0_h, N, 1);

    // ---- layer 1 (H=4) ----
    mfma_dual<32, 128><<<rowBlocks * 4, 256, 0, stream>>>(H0_h, c1Wlt, c1Wrt, Xl_h, Xr_h, N);
    gat8_h4<<<cdiv(N, 32), 256, 0, stream>>>(Xl_h, Xr_h, att1h, offsets, counts, adj, c1_b, H1_h, N);

    // ---- layer 2 (H=4) ----
    mfma_dual<128, 128><<<rowBlocks * 4, 256, 0, stream>>>(H1_h, c2Wlt, c2Wrt, Xl_h, Xr_h, N);
    gat8_h4<<<cdiv(N, 32), 256, 0, stream>>>(Xl_h, Xr_h, att2h, offsets, counts, adj, c2_b, AF_h, N);

    // ---- global graph (H=1) ----
    mfma_dual<128, 32><<<rowBlocks * 1, 256, 0, stream>>>(AF_h, ggWlt, ggWrt, Xl_h, Xr_h, N);
    gat8_h1<<<cdiv(N, 32), 256, 0, stream>>>(Xl_h, Xr_h, attgh, offsets, counts, adj, gg_b, GF_f, N);

    // ---- map branch ----
    hipMemsetAsync(MAPS, 0, 32 * sizeof(float), stream);
    map_sum_kernel<<<64, BS, 0, stream>>>(lane_x, map_W, map_b, MAPS, M);

    // ---- fused head ----
    head_kernel<<<F, 64, 0, stream>>>(GF_f, focal_idx, MAPS, M, centerline, L,
                                      cl_W, cl_b, fc1_W, fc1_b, fc2_W, fc2_b,
                                      fco_W, fco_b, (float*)d_out);
}